// Round 1
// baseline (2208.732 us; speedup 1.0000x reference)
//
#include <hip/hip_runtime.h>

#define N_NODES 50000
#define N_EDGES 800000
#define IN_DIM  128
#define HID_DIM 128
#define OUT_DIM 64

// ---------------- degree / dinv ----------------

__global__ void deg_kernel(const int* __restrict__ dst, float* __restrict__ deg) {
    int e = blockIdx.x * 256 + threadIdx.x;
    if (e < N_EDGES) atomicAdd(&deg[dst[e]], 1.0f);
}

__global__ void dinv_kernel(float* __restrict__ deg) {
    int n = blockIdx.x * 256 + threadIdx.x;
    if (n < N_NODES) {
        float d = deg[n];
        deg[n] = (d > 0.0f) ? rsqrtf(d) : 0.0f;   // matches where(deg>0, rsqrt(max(deg,1)), 0)
    }
}

// ---------------- init buffer to broadcast bias ----------------
// buf[n][c] = b[c], vectorized float4. dim4 = dim/4.

__global__ void init_bias4_kernel(float4* __restrict__ buf, const float* __restrict__ b,
                                  int total4, int dim4) {
    int i = blockIdx.x * 256 + threadIdx.x;
    if (i >= total4) return;
    int c4 = i % dim4;
    buf[i] = ((const float4*)b)[c4];
}

// ---------------- GEMM1: h1 = x @ W1   [50000x128] = [50000x128]@[128x128] ----------------
// block 256 threads -> 32 rows x 128 cols; thread = 4 rows x 4 cols (float4)

__global__ __launch_bounds__(256) void gemm1_kernel(const float* __restrict__ x,
                                                    const float* __restrict__ W,
                                                    float* __restrict__ h) {
    __shared__ float Wds[128 * 128];   // 64 KB
    __shared__ float xs[32 * 128];     // 16 KB

    float4* Wds4 = (float4*)Wds;
    const float4* W4 = (const float4*)W;
    for (int i = threadIdx.x; i < 128 * 128 / 4; i += 256) Wds4[i] = W4[i];

    int row0 = blockIdx.x * 32;
    int nrows = min(32, N_NODES - row0);
    const float4* x4 = (const float4*)(x + (size_t)row0 * 128);
    float4* xs4 = (float4*)xs;
    for (int i = threadIdx.x; i < nrows * 32; i += 256) xs4[i] = x4[i];
    __syncthreads();

    int tx = threadIdx.x & 31;   // col4 index: cols tx*4 .. tx*4+3
    int ty = threadIdx.x >> 5;   // row group: rows ty*4 .. ty*4+3
    float4 acc[4] = {};

#pragma unroll 4
    for (int k = 0; k < 128; ++k) {
        float4 w = Wds4[k * 32 + tx];
#pragma unroll
        for (int r = 0; r < 4; ++r) {
            float xv = xs[(ty * 4 + r) * 128 + k];
            acc[r].x += xv * w.x;
            acc[r].y += xv * w.y;
            acc[r].z += xv * w.z;
            acc[r].w += xv * w.w;
        }
    }

#pragma unroll
    for (int r = 0; r < 4; ++r) {
        int row = row0 + ty * 4 + r;
        if (row < N_NODES) ((float4*)(h + (size_t)row * 128))[tx] = acc[r];
    }
}

// ---------------- GEMM2: h2 = relu(a1) @ W2   [50000x64] = [50000x128]@[128x64] ----------------
// block 256 threads -> 64 rows x 64 cols; thread = 4 rows x 4 cols

__global__ __launch_bounds__(256) void gemm2_kernel(const float* __restrict__ a1,
                                                    const float* __restrict__ W,
                                                    float* __restrict__ h2) {
    __shared__ float Wds[128 * 64];    // 32 KB
    __shared__ float xs[64 * 128];     // 32 KB

    float4* Wds4 = (float4*)Wds;
    const float4* W4 = (const float4*)W;
    for (int i = threadIdx.x; i < 128 * 64 / 4; i += 256) Wds4[i] = W4[i];

    int row0 = blockIdx.x * 64;
    int nrows = min(64, N_NODES - row0);
    const float4* a4 = (const float4*)(a1 + (size_t)row0 * 128);
    float4* xs4 = (float4*)xs;
    for (int i = threadIdx.x; i < nrows * 32; i += 256) {
        float4 v = a4[i];                       // fused relu on stage-in
        v.x = fmaxf(v.x, 0.0f); v.y = fmaxf(v.y, 0.0f);
        v.z = fmaxf(v.z, 0.0f); v.w = fmaxf(v.w, 0.0f);
        xs4[i] = v;
    }
    __syncthreads();

    int tx = threadIdx.x & 15;   // col4: cols tx*4..tx*4+3 (of 64)
    int ty = threadIdx.x >> 4;   // row group: rows ty*4..ty*4+3 (of 64)
    float4 acc[4] = {};

#pragma unroll 4
    for (int k = 0; k < 128; ++k) {
        float4 w = Wds4[k * 16 + tx];
#pragma unroll
        for (int r = 0; r < 4; ++r) {
            float xv = xs[(ty * 4 + r) * 128 + k];
            acc[r].x += xv * w.x;
            acc[r].y += xv * w.y;
            acc[r].z += xv * w.z;
            acc[r].w += xv * w.w;
        }
    }

#pragma unroll
    for (int r = 0; r < 4; ++r) {
        int row = row0 + ty * 4 + r;
        if (row < N_NODES) ((float4*)(h2 + (size_t)row * 64))[tx] = acc[r];
    }
}

// ---------------- scatter1: a1[dst] += h1[src] * norm, 128 ch ----------------
// 8 edges per 256-block, 32 lanes/edge, float4 per lane

__global__ __launch_bounds__(256) void scatter1_kernel(const int* __restrict__ src,
                                                       const int* __restrict__ dst,
                                                       const float* __restrict__ dinv,
                                                       const float* __restrict__ h1,
                                                       float* __restrict__ a1) {
    int t = threadIdx.x;
    int e = blockIdx.x * 8 + (t >> 5);
    if (e >= N_EDGES) return;
    int lane = t & 31;
    int s = src[e], d = dst[e];
    float norm = dinv[s] * dinv[d];
    float4 v = ((const float4*)(h1 + (size_t)s * 128))[lane];
    float* out = a1 + (size_t)d * 128 + lane * 4;
    atomicAdd(out + 0, v.x * norm);
    atomicAdd(out + 1, v.y * norm);
    atomicAdd(out + 2, v.z * norm);
    atomicAdd(out + 3, v.w * norm);
}

// ---------------- scatter2: out[dst] += h2[src] * norm, 64 ch ----------------
// 16 edges per 256-block, 16 lanes/edge, float4 per lane

__global__ __launch_bounds__(256) void scatter2_kernel(const int* __restrict__ src,
                                                       const int* __restrict__ dst,
                                                       const float* __restrict__ dinv,
                                                       const float* __restrict__ h2,
                                                       float* __restrict__ out) {
    int t = threadIdx.x;
    int e = blockIdx.x * 16 + (t >> 4);
    if (e >= N_EDGES) return;
    int lane = t & 15;
    int s = src[e], d = dst[e];
    float norm = dinv[s] * dinv[d];
    float4 v = ((const float4*)(h2 + (size_t)s * 64))[lane];
    float* o = out + (size_t)d * 64 + lane * 4;
    atomicAdd(o + 0, v.x * norm);
    atomicAdd(o + 1, v.y * norm);
    atomicAdd(o + 2, v.z * norm);
    atomicAdd(o + 3, v.w * norm);
}

// ---------------- launch ----------------

extern "C" void kernel_launch(void* const* d_in, const int* in_sizes, int n_in,
                              void* d_out, int out_size, void* d_ws, size_t ws_size,
                              hipStream_t stream) {
    const float* x  = (const float*)d_in[0];
    const int*   ei = (const int*)d_in[1];       // [2, E]: src = ei[0..E), dst = ei[E..2E)
    const float* W1 = (const float*)d_in[2];
    const float* b1 = (const float*)d_in[3];
    const float* W2 = (const float*)d_in[4];
    const float* b2 = (const float*)d_in[5];
    float* out = (float*)d_out;

    const int* src = ei;
    const int* dst = ei + N_EDGES;

    // workspace layout (floats)
    float* ws  = (float*)d_ws;
    float* deg = ws;                       // 50000 floats (becomes dinv in-place)
    float* h1  = ws + 65536;               // 50000*128
    float* a1  = h1 + (size_t)N_NODES * HID_DIM;
    float* h2  = a1 + (size_t)N_NODES * HID_DIM;

    // 1. degree -> dinv
    hipMemsetAsync(deg, 0, N_NODES * sizeof(float), stream);
    deg_kernel<<<(N_EDGES + 255) / 256, 256, 0, stream>>>(dst, deg);
    dinv_kernel<<<(N_NODES + 255) / 256, 256, 0, stream>>>(deg);

    // 2. h1 = x @ W1
    gemm1_kernel<<<(N_NODES + 31) / 32, 256, 0, stream>>>(x, W1, h1);

    // 3. a1 = b1 (broadcast), then scatter-add normalized messages
    {
        int total4 = N_NODES * HID_DIM / 4;
        init_bias4_kernel<<<(total4 + 255) / 256, 256, 0, stream>>>((float4*)a1, b1, total4, HID_DIM / 4);
    }
    scatter1_kernel<<<(N_EDGES + 7) / 8, 256, 0, stream>>>(src, dst, deg, h1, a1);

    // 4. h2 = relu(a1) @ W2
    gemm2_kernel<<<(N_NODES + 63) / 64, 256, 0, stream>>>(a1, W2, h2);

    // 5. out = b2 (broadcast), then scatter-add
    {
        int total4 = N_NODES * OUT_DIM / 4;
        init_bias4_kernel<<<(total4 + 255) / 256, 256, 0, stream>>>((float4*)out, b2, total4, OUT_DIM / 4);
    }
    scatter2_kernel<<<(N_EDGES + 15) / 16, 256, 0, stream>>>(src, dst, deg, h2, out);
}

// Round 2
// 391.815 us; speedup vs baseline: 5.6372x; 5.6372x over previous
//
#include <hip/hip_runtime.h>

#define N_NODES 50000
#define N_EDGES 800000
#define IN_DIM  128
#define HID_DIM 128
#define OUT_DIM 64

#define NPAD 50176                      // N_NODES rounded up (alignment)
#define NB_SCAN ((N_NODES + 1023) / 1024)   // 49

// ---------------- CSR build: histogram of dst ----------------

__global__ void hist_kernel(const int* __restrict__ dst, int* __restrict__ cnt) {
    int e = blockIdx.x * 256 + threadIdx.x;
    if (e < N_EDGES) atomicAdd(&cnt[dst[e]], 1);
}

// dinv[n] = cnt[n] > 0 ? rsqrt(cnt[n]) : 0
__global__ void dinv_kernel(const int* __restrict__ cnt, float* __restrict__ dinv) {
    int n = blockIdx.x * 256 + threadIdx.x;
    if (n < N_NODES) {
        int d = cnt[n];
        dinv[n] = (d > 0) ? rsqrtf((float)d) : 0.0f;
    }
}

// ---------------- exclusive scan of cnt -> row_start (3 kernels) ----------------

__global__ __launch_bounds__(1024) void reduce_kernel(const int* __restrict__ cnt,
                                                      int* __restrict__ blockSums) {
    __shared__ int s[1024];
    int i = blockIdx.x * 1024 + threadIdx.x;
    s[threadIdx.x] = (i < N_NODES) ? cnt[i] : 0;
    __syncthreads();
    for (int off = 512; off > 0; off >>= 1) {
        if (threadIdx.x < off) s[threadIdx.x] += s[threadIdx.x + off];
        __syncthreads();
    }
    if (threadIdx.x == 0) blockSums[blockIdx.x] = s[0];
}

__global__ void scan_sums_kernel(int* __restrict__ blockSums) {
    if (threadIdx.x == 0) {
        int run = 0;
        for (int i = 0; i < NB_SCAN; ++i) { int t = blockSums[i]; blockSums[i] = run; run += t; }
    }
}

__global__ __launch_bounds__(1024) void scan_kernel(const int* __restrict__ cnt,
                                                    const int* __restrict__ blockSums,
                                                    int* __restrict__ row_start) {
    __shared__ int s[1024];
    int i = blockIdx.x * 1024 + threadIdx.x;
    int v = (i < N_NODES) ? cnt[i] : 0;
    s[threadIdx.x] = v;
    __syncthreads();
    for (int off = 1; off < 1024; off <<= 1) {
        int t = (threadIdx.x >= off) ? s[threadIdx.x - off] : 0;
        __syncthreads();
        s[threadIdx.x] += t;
        __syncthreads();
    }
    if (i < N_NODES) row_start[i] = blockSums[blockIdx.x] + s[threadIdx.x] - v;  // exclusive
}

// ---------------- fill CSR: (src, norm) sorted by dst ----------------

__global__ void fill_kernel(const int* __restrict__ src, const int* __restrict__ dst,
                            const float* __restrict__ dinv, const int* __restrict__ row_start,
                            int* __restrict__ cursor, int* __restrict__ csr_src,
                            float* __restrict__ csr_norm) {
    int e = blockIdx.x * 256 + threadIdx.x;
    if (e >= N_EDGES) return;
    int s = src[e], d = dst[e];
    int pos = row_start[d] + atomicAdd(&cursor[d], 1);
    csr_src[pos] = s;
    csr_norm[pos] = dinv[s] * dinv[d];
}

// ---------------- GEMM1: h1 = x @ W1   [50000x128] = [50000x128]@[128x128] ----------------

__global__ __launch_bounds__(256) void gemm1_kernel(const float* __restrict__ x,
                                                    const float* __restrict__ W,
                                                    float* __restrict__ h) {
    __shared__ float Wds[128 * 128];   // 64 KB
    __shared__ float xs[32 * 128];     // 16 KB

    float4* Wds4 = (float4*)Wds;
    const float4* W4 = (const float4*)W;
    for (int i = threadIdx.x; i < 128 * 128 / 4; i += 256) Wds4[i] = W4[i];

    int row0 = blockIdx.x * 32;
    int nrows = min(32, N_NODES - row0);
    const float4* x4 = (const float4*)(x + (size_t)row0 * 128);
    float4* xs4 = (float4*)xs;
    for (int i = threadIdx.x; i < nrows * 32; i += 256) xs4[i] = x4[i];
    __syncthreads();

    int tx = threadIdx.x & 31;
    int ty = threadIdx.x >> 5;
    float4 acc[4] = {};

#pragma unroll 4
    for (int k = 0; k < 128; ++k) {
        float4 w = Wds4[k * 32 + tx];
#pragma unroll
        for (int r = 0; r < 4; ++r) {
            float xv = xs[(ty * 4 + r) * 128 + k];
            acc[r].x += xv * w.x;
            acc[r].y += xv * w.y;
            acc[r].z += xv * w.z;
            acc[r].w += xv * w.w;
        }
    }

#pragma unroll
    for (int r = 0; r < 4; ++r) {
        int row = row0 + ty * 4 + r;
        if (row < N_NODES) ((float4*)(h + (size_t)row * 128))[tx] = acc[r];
    }
}

// ---------------- agg1: a1[n] = relu(b1 + sum_{e: dst=n} norm_e * h1[src_e])  [128 ch] ----------
// 1 wave (64 lanes) per node; lane handles 2 channels (float2). 4 nodes per 256-block.

__global__ __launch_bounds__(256) void agg1_kernel(const int* __restrict__ csr_src,
                                                   const float* __restrict__ csr_norm,
                                                   const int* __restrict__ row_start,
                                                   const int* __restrict__ cnt,
                                                   const float* __restrict__ b1,
                                                   const float* __restrict__ h1,
                                                   float* __restrict__ a1) {
    int node = blockIdx.x * 4 + (threadIdx.x >> 6);
    if (node >= N_NODES) return;
    int lane = threadIdx.x & 63;
    int start = row_start[node];
    int m = cnt[node];

    float2 acc = *(const float2*)(b1 + lane * 2);
    for (int j = 0; j < m; ++j) {
        int s = csr_src[start + j];
        float nrm = csr_norm[start + j];
        float2 v = *(const float2*)(h1 + (size_t)s * 128 + lane * 2);
        acc.x += v.x * nrm;
        acc.y += v.y * nrm;
    }
    acc.x = fmaxf(acc.x, 0.0f);       // fused relu (reference: relu(conv+bias))
    acc.y = fmaxf(acc.y, 0.0f);
    *(float2*)(a1 + (size_t)node * 128 + lane * 2) = acc;
}

// ---------------- GEMM2: h2 = a1 @ W2   [50000x64] = [50000x128]@[128x64] (relu already applied)

__global__ __launch_bounds__(256) void gemm2_kernel(const float* __restrict__ a1,
                                                    const float* __restrict__ W,
                                                    float* __restrict__ h2) {
    __shared__ float Wds[128 * 64];    // 32 KB
    __shared__ float xs[64 * 128];     // 32 KB

    float4* Wds4 = (float4*)Wds;
    const float4* W4 = (const float4*)W;
    for (int i = threadIdx.x; i < 128 * 64 / 4; i += 256) Wds4[i] = W4[i];

    int row0 = blockIdx.x * 64;
    int nrows = min(64, N_NODES - row0);
    const float4* a4 = (const float4*)(a1 + (size_t)row0 * 128);
    float4* xs4 = (float4*)xs;
    for (int i = threadIdx.x; i < nrows * 32; i += 256) xs4[i] = a4[i];
    __syncthreads();

    int tx = threadIdx.x & 15;
    int ty = threadIdx.x >> 4;
    float4 acc[4] = {};

#pragma unroll 4
    for (int k = 0; k < 128; ++k) {
        float4 w = Wds4[k * 16 + tx];
#pragma unroll
        for (int r = 0; r < 4; ++r) {
            float xv = xs[(ty * 4 + r) * 128 + k];
            acc[r].x += xv * w.x;
            acc[r].y += xv * w.y;
            acc[r].z += xv * w.z;
            acc[r].w += xv * w.w;
        }
    }

#pragma unroll
    for (int r = 0; r < 4; ++r) {
        int row = row0 + ty * 4 + r;
        if (row < N_NODES) ((float4*)(h2 + (size_t)row * 64))[tx] = acc[r];
    }
}

// ---------------- agg2: out[n] = b2 + sum norm_e * h2[src_e]  [64 ch] ----------
// 1 wave per node; lane handles 1 channel. 4 nodes per 256-block.

__global__ __launch_bounds__(256) void agg2_kernel(const int* __restrict__ csr_src,
                                                   const float* __restrict__ csr_norm,
                                                   const int* __restrict__ row_start,
                                                   const int* __restrict__ cnt,
                                                   const float* __restrict__ b2,
                                                   const float* __restrict__ h2,
                                                   float* __restrict__ out) {
    int node = blockIdx.x * 4 + (threadIdx.x >> 6);
    if (node >= N_NODES) return;
    int lane = threadIdx.x & 63;
    int start = row_start[node];
    int m = cnt[node];

    float acc = b2[lane];
    for (int j = 0; j < m; ++j) {
        int s = csr_src[start + j];
        float nrm = csr_norm[start + j];
        acc += h2[(size_t)s * 64 + lane] * nrm;
    }
    out[(size_t)node * 64 + lane] = acc;
}

// ---------------- launch ----------------

extern "C" void kernel_launch(void* const* d_in, const int* in_sizes, int n_in,
                              void* d_out, int out_size, void* d_ws, size_t ws_size,
                              hipStream_t stream) {
    const float* x  = (const float*)d_in[0];
    const int*   ei = (const int*)d_in[1];       // [2, E]: src = ei[0..E), dst = ei[E..2E)
    const float* W1 = (const float*)d_in[2];
    const float* b1 = (const float*)d_in[3];
    const float* W2 = (const float*)d_in[4];
    const float* b2 = (const float*)d_in[5];
    float* out = (float*)d_out;

    const int* src = ei;
    const int* dst = ei + N_EDGES;

    // workspace layout (32-bit words)
    char* ws = (char*)d_ws;
    int*   cnt       = (int*)ws;                              // NPAD
    int*   cursor    = cnt + NPAD;                            // NPAD  (adjacent -> one memset)
    int*   row_start = cursor + NPAD;                         // NPAD
    int*   blockSums = row_start + NPAD;                      // 64
    float* dinv      = (float*)(blockSums + 64);              // NPAD
    int*   csr_src   = (int*)(dinv + NPAD);                   // N_EDGES
    float* csr_norm  = (float*)(csr_src + N_EDGES);           // N_EDGES
    float* h1        = csr_norm + N_EDGES;                    // 50000*128 (h2 aliases h1)
    float* a1        = h1 + (size_t)N_NODES * HID_DIM;        // 50000*128
    float* h2        = h1;                                    // reuse: h1 dead after agg1

    // 1. zero cnt+cursor, histogram dst, dinv
    hipMemsetAsync(cnt, 0, 2 * NPAD * sizeof(int), stream);
    hist_kernel<<<(N_EDGES + 255) / 256, 256, 0, stream>>>(dst, cnt);
    dinv_kernel<<<(N_NODES + 255) / 256, 256, 0, stream>>>(cnt, dinv);

    // 2. exclusive scan cnt -> row_start
    reduce_kernel<<<NB_SCAN, 1024, 0, stream>>>(cnt, blockSums);
    scan_sums_kernel<<<1, 64, 0, stream>>>(blockSums);
    scan_kernel<<<NB_SCAN, 1024, 0, stream>>>(cnt, blockSums, row_start);

    // 3. fill CSR (src, norm)
    fill_kernel<<<(N_EDGES + 255) / 256, 256, 0, stream>>>(src, dst, dinv, row_start,
                                                           cursor, csr_src, csr_norm);

    // 4. h1 = x @ W1
    gemm1_kernel<<<(N_NODES + 31) / 32, 256, 0, stream>>>(x, W1, h1);

    // 5. a1 = relu(b1 + gather-sum)
    agg1_kernel<<<(N_NODES + 3) / 4, 256, 0, stream>>>(csr_src, csr_norm, row_start, cnt, b1, h1, a1);

    // 6. h2 = a1 @ W2
    gemm2_kernel<<<(N_NODES + 63) / 64, 256, 0, stream>>>(a1, W2, h2);

    // 7. out = b2 + gather-sum
    agg2_kernel<<<(N_NODES + 3) / 4, 256, 0, stream>>>(csr_src, csr_norm, row_start, cnt, b2, h2, out);
}

// Round 3
// 311.766 us; speedup vs baseline: 7.0846x; 1.2568x over previous
//
#include <hip/hip_runtime.h>

#define N_NODES 50000
#define N_EDGES 800000
#define IN_DIM  128
#define HID_DIM 128
#define OUT_DIM 64

#define NPAD 50176                          // N_NODES rounded up (alignment)
#define NB_SCAN ((N_NODES + 1023) / 1024)   // 49

// ---------------- CSR build: histogram of dst ----------------

__global__ void hist_kernel(const int* __restrict__ dst, int* __restrict__ cnt) {
    int e = blockIdx.x * 256 + threadIdx.x;
    if (e < N_EDGES) atomicAdd(&cnt[dst[e]], 1);
}

// dinv[n] = cnt[n] > 0 ? rsqrt(cnt[n]) : 0
__global__ void dinv_kernel(const int* __restrict__ cnt, float* __restrict__ dinv) {
    int n = blockIdx.x * 256 + threadIdx.x;
    if (n < N_NODES) {
        int d = cnt[n];
        dinv[n] = (d > 0) ? rsqrtf((float)d) : 0.0f;
    }
}

// ---------------- exclusive scan of cnt -> row_start ----------------

__global__ __launch_bounds__(1024) void reduce_kernel(const int* __restrict__ cnt,
                                                      int* __restrict__ blockSums) {
    __shared__ int s[1024];
    int i = blockIdx.x * 1024 + threadIdx.x;
    s[threadIdx.x] = (i < N_NODES) ? cnt[i] : 0;
    __syncthreads();
    for (int off = 512; off > 0; off >>= 1) {
        if (threadIdx.x < off) s[threadIdx.x] += s[threadIdx.x + off];
        __syncthreads();
    }
    if (threadIdx.x == 0) blockSums[blockIdx.x] = s[0];
}

__global__ void scan_sums_kernel(int* __restrict__ blockSums) {
    if (threadIdx.x == 0) {
        int run = 0;
        for (int i = 0; i < NB_SCAN; ++i) { int t = blockSums[i]; blockSums[i] = run; run += t; }
    }
}

__global__ __launch_bounds__(1024) void scan_kernel(const int* __restrict__ cnt,
                                                    const int* __restrict__ blockSums,
                                                    int* __restrict__ row_start) {
    __shared__ int s[1024];
    int i = blockIdx.x * 1024 + threadIdx.x;
    int v = (i < N_NODES) ? cnt[i] : 0;
    s[threadIdx.x] = v;
    __syncthreads();
    for (int off = 1; off < 1024; off <<= 1) {
        int t = (threadIdx.x >= off) ? s[threadIdx.x - off] : 0;
        __syncthreads();
        s[threadIdx.x] += t;
        __syncthreads();
    }
    if (i < N_NODES) row_start[i] = blockSums[blockIdx.x] + s[threadIdx.x] - v;  // exclusive
}

// ---------------- fill CSR: packed (src, norm) sorted by dst ----------------

__global__ void fill_kernel(const int* __restrict__ src, const int* __restrict__ dst,
                            const float* __restrict__ dinv, const int* __restrict__ row_start,
                            int* __restrict__ cursor, int2* __restrict__ csr) {
    int e = blockIdx.x * 256 + threadIdx.x;
    if (e >= N_EDGES) return;
    int s = src[e], d = dst[e];
    int pos = row_start[d] + atomicAdd(&cursor[d], 1);
    csr[pos] = make_int2(s, __float_as_int(dinv[s] * dinv[d]));
}

// ---------------- GEMM1: h1 = x @ W1   [50000x128] = [50000x128]@[128x128] ----------------

__global__ __launch_bounds__(256) void gemm1_kernel(const float* __restrict__ x,
                                                    const float* __restrict__ W,
                                                    float* __restrict__ h) {
    __shared__ float Wds[128 * 128];   // 64 KB
    __shared__ float xs[32 * 128];     // 16 KB

    float4* Wds4 = (float4*)Wds;
    const float4* W4 = (const float4*)W;
    for (int i = threadIdx.x; i < 128 * 128 / 4; i += 256) Wds4[i] = W4[i];

    int row0 = blockIdx.x * 32;
    int nrows = min(32, N_NODES - row0);
    const float4* x4 = (const float4*)(x + (size_t)row0 * 128);
    float4* xs4 = (float4*)xs;
    for (int i = threadIdx.x; i < nrows * 32; i += 256) xs4[i] = x4[i];
    __syncthreads();

    int tx = threadIdx.x & 31;
    int ty = threadIdx.x >> 5;
    float4 acc[4] = {};

#pragma unroll 4
    for (int k = 0; k < 128; ++k) {
        float4 w = Wds4[k * 32 + tx];
#pragma unroll
        for (int r = 0; r < 4; ++r) {
            float xv = xs[(ty * 4 + r) * 128 + k];
            acc[r].x += xv * w.x;
            acc[r].y += xv * w.y;
            acc[r].z += xv * w.z;
            acc[r].w += xv * w.w;
        }
    }

#pragma unroll
    for (int r = 0; r < 4; ++r) {
        int row = row0 + ty * 4 + r;
        if (row < N_NODES) ((float4*)(h + (size_t)row * 128))[tx] = acc[r];
    }
}

// ---------------- agg1: a1[n] = relu(b1 + sum norm_e * h1[src_e])  [128 ch] ----------
// 1 wave/node. Wave split in 2 halves of 32 lanes (float4 = full 512B row each);
// halves process even/odd edges concurrently; unroll 2 -> 4 gathers in flight.

__global__ __launch_bounds__(256) void agg1_kernel(const int2* __restrict__ csr,
                                                   const int* __restrict__ row_start,
                                                   const int* __restrict__ cnt,
                                                   const float* __restrict__ b1,
                                                   const float* __restrict__ h1,
                                                   float* __restrict__ a1) {
    int node = blockIdx.x * 4 + (threadIdx.x >> 6);
    if (node >= N_NODES) return;
    int lane = threadIdx.x & 63;
    int half = lane >> 5;        // which edge of the pair
    int q    = lane & 31;        // float4 slot within the 128-ch row
    int start = row_start[node];
    int m = cnt[node];

    float4 acc = make_float4(0.f, 0.f, 0.f, 0.f);
#pragma unroll 2
    for (int j = half; j < m; j += 2) {
        int2 p = csr[start + j];
        float nrm = __int_as_float(p.y);
        float4 v = ((const float4*)(h1 + (size_t)p.x * 128))[q];
        acc.x += v.x * nrm;
        acc.y += v.y * nrm;
        acc.z += v.z * nrm;
        acc.w += v.w * nrm;
    }
    // reduce across the two halves
    acc.x += __shfl_xor(acc.x, 32, 64);
    acc.y += __shfl_xor(acc.y, 32, 64);
    acc.z += __shfl_xor(acc.z, 32, 64);
    acc.w += __shfl_xor(acc.w, 32, 64);

    if (half == 0) {
        float4 bb = ((const float4*)b1)[q];
        float4 r;
        r.x = fmaxf(acc.x + bb.x, 0.f);
        r.y = fmaxf(acc.y + bb.y, 0.f);
        r.z = fmaxf(acc.z + bb.z, 0.f);
        r.w = fmaxf(acc.w + bb.w, 0.f);
        ((float4*)(a1 + (size_t)node * 128))[q] = r;
    }
}

// ---------------- GEMM2: h2 = a1 @ W2   [50000x64] = [50000x128]@[128x64] ----------------

__global__ __launch_bounds__(256) void gemm2_kernel(const float* __restrict__ a1,
                                                    const float* __restrict__ W,
                                                    float* __restrict__ h2) {
    __shared__ float Wds[128 * 64];    // 32 KB
    __shared__ float xs[64 * 128];     // 32 KB

    float4* Wds4 = (float4*)Wds;
    const float4* W4 = (const float4*)W;
    for (int i = threadIdx.x; i < 128 * 64 / 4; i += 256) Wds4[i] = W4[i];

    int row0 = blockIdx.x * 64;
    int nrows = min(64, N_NODES - row0);
    const float4* a4 = (const float4*)(a1 + (size_t)row0 * 128);
    float4* xs4 = (float4*)xs;
    for (int i = threadIdx.x; i < nrows * 32; i += 256) xs4[i] = a4[i];
    __syncthreads();

    int tx = threadIdx.x & 15;
    int ty = threadIdx.x >> 4;
    float4 acc[4] = {};

#pragma unroll 4
    for (int k = 0; k < 128; ++k) {
        float4 w = Wds4[k * 16 + tx];
#pragma unroll
        for (int r = 0; r < 4; ++r) {
            float xv = xs[(ty * 4 + r) * 128 + k];
            acc[r].x += xv * w.x;
            acc[r].y += xv * w.y;
            acc[r].z += xv * w.z;
            acc[r].w += xv * w.w;
        }
    }

#pragma unroll
    for (int r = 0; r < 4; ++r) {
        int row = row0 + ty * 4 + r;
        if (row < N_NODES) ((float4*)(h2 + (size_t)row * 64))[tx] = acc[r];
    }
}

// ---------------- agg2: out[n] = b2 + sum norm_e * h2[src_e]  [64 ch] ----------
// 1 wave/node. 4 groups of 16 lanes (float4 = full 256B row); 4 edges in flight.

__global__ __launch_bounds__(256) void agg2_kernel(const int2* __restrict__ csr,
                                                   const int* __restrict__ row_start,
                                                   const int* __restrict__ cnt,
                                                   const float* __restrict__ b2,
                                                   const float* __restrict__ h2,
                                                   float* __restrict__ out) {
    int node = blockIdx.x * 4 + (threadIdx.x >> 6);
    if (node >= N_NODES) return;
    int lane = threadIdx.x & 63;
    int grp = lane >> 4;         // 0..3: which edge of the quad
    int q   = lane & 15;         // float4 slot within the 64-ch row
    int start = row_start[node];
    int m = cnt[node];

    float4 acc = make_float4(0.f, 0.f, 0.f, 0.f);
#pragma unroll 2
    for (int j = grp; j < m; j += 4) {
        int2 p = csr[start + j];
        float nrm = __int_as_float(p.y);
        float4 v = ((const float4*)(h2 + (size_t)p.x * 64))[q];
        acc.x += v.x * nrm;
        acc.y += v.y * nrm;
        acc.z += v.z * nrm;
        acc.w += v.w * nrm;
    }
    // reduce across 4 groups
    acc.x += __shfl_xor(acc.x, 32, 64);
    acc.y += __shfl_xor(acc.y, 32, 64);
    acc.z += __shfl_xor(acc.z, 32, 64);
    acc.w += __shfl_xor(acc.w, 32, 64);
    acc.x += __shfl_xor(acc.x, 16, 64);
    acc.y += __shfl_xor(acc.y, 16, 64);
    acc.z += __shfl_xor(acc.z, 16, 64);
    acc.w += __shfl_xor(acc.w, 16, 64);

    if (grp == 0) {
        float4 bb = ((const float4*)b2)[q];
        float4 r;
        r.x = acc.x + bb.x;
        r.y = acc.y + bb.y;
        r.z = acc.z + bb.z;
        r.w = acc.w + bb.w;
        ((float4*)(out + (size_t)node * 64))[q] = r;
    }
}

// ---------------- launch ----------------

extern "C" void kernel_launch(void* const* d_in, const int* in_sizes, int n_in,
                              void* d_out, int out_size, void* d_ws, size_t ws_size,
                              hipStream_t stream) {
    const float* x  = (const float*)d_in[0];
    const int*   ei = (const int*)d_in[1];       // [2, E]: src = ei[0..E), dst = ei[E..2E)
    const float* W1 = (const float*)d_in[2];
    const float* b1 = (const float*)d_in[3];
    const float* W2 = (const float*)d_in[4];
    const float* b2 = (const float*)d_in[5];
    float* out = (float*)d_out;

    const int* src = ei;
    const int* dst = ei + N_EDGES;

    // workspace layout (32-bit words)
    char* ws = (char*)d_ws;
    int*   cnt       = (int*)ws;                              // NPAD
    int*   cursor    = cnt + NPAD;                            // NPAD  (adjacent -> one memset)
    int*   row_start = cursor + NPAD;                         // NPAD
    int*   blockSums = row_start + NPAD;                      // 64
    float* dinv      = (float*)(blockSums + 64);              // NPAD
    int2*  csr       = (int2*)(dinv + NPAD);                  // N_EDGES int2 (8B aligned: offsets even)
    float* h1        = (float*)(csr + N_EDGES);               // 50000*128 (h2 aliases h1)
    float* a1        = h1 + (size_t)N_NODES * HID_DIM;        // 50000*128
    float* h2        = h1;                                    // reuse: h1 dead after agg1

    // 1. zero cnt+cursor, histogram dst, dinv
    hipMemsetAsync(cnt, 0, 2 * NPAD * sizeof(int), stream);
    hist_kernel<<<(N_EDGES + 255) / 256, 256, 0, stream>>>(dst, cnt);
    dinv_kernel<<<(N_NODES + 255) / 256, 256, 0, stream>>>(cnt, dinv);

    // 2. exclusive scan cnt -> row_start
    reduce_kernel<<<NB_SCAN, 1024, 0, stream>>>(cnt, blockSums);
    scan_sums_kernel<<<1, 64, 0, stream>>>(blockSums);
    scan_kernel<<<NB_SCAN, 1024, 0, stream>>>(cnt, blockSums, row_start);

    // 3. fill CSR (packed src, norm)
    fill_kernel<<<(N_EDGES + 255) / 256, 256, 0, stream>>>(src, dst, dinv, row_start,
                                                           cursor, csr);

    // 4. h1 = x @ W1
    gemm1_kernel<<<(N_NODES + 31) / 32, 256, 0, stream>>>(x, W1, h1);

    // 5. a1 = relu(b1 + gather-sum)
    agg1_kernel<<<(N_NODES + 3) / 4, 256, 0, stream>>>(csr, row_start, cnt, b1, h1, a1);

    // 6. h2 = a1 @ W2
    gemm2_kernel<<<(N_NODES + 63) / 64, 256, 0, stream>>>(a1, W2, h2);

    // 7. out = b2 + gather-sum
    agg2_kernel<<<(N_NODES + 3) / 4, 256, 0, stream>>>(csr, row_start, cnt, b2, h2, out);
}

// Round 4
// 309.751 us; speedup vs baseline: 7.1307x; 1.0065x over previous
//
#include <hip/hip_runtime.h>

#define N_NODES 50000
#define N_EDGES 800000
#define IN_DIM  128
#define HID_DIM 128
#define OUT_DIM 64

#define NPAD 50176                          // N_NODES rounded up (alignment)
#define NB_SCAN ((N_NODES + 1023) / 1024)   // 49

// ---------------- CSR build: histogram of dst ----------------

__global__ void hist_kernel(const int* __restrict__ dst, int* __restrict__ cnt) {
    int e = blockIdx.x * 256 + threadIdx.x;
    if (e < N_EDGES) atomicAdd(&cnt[dst[e]], 1);
}

// ---------------- exclusive scan of cnt -> row_start ----------------

__global__ __launch_bounds__(1024) void reduce_kernel(const int* __restrict__ cnt,
                                                      int* __restrict__ blockSums) {
    __shared__ int s[1024];
    int i = blockIdx.x * 1024 + threadIdx.x;
    s[threadIdx.x] = (i < N_NODES) ? cnt[i] : 0;
    __syncthreads();
    for (int off = 512; off > 0; off >>= 1) {
        if (threadIdx.x < off) s[threadIdx.x] += s[threadIdx.x + off];
        __syncthreads();
    }
    if (threadIdx.x == 0) blockSums[blockIdx.x] = s[0];
}

__global__ void scan_sums_kernel(int* __restrict__ blockSums) {
    if (threadIdx.x == 0) {
        int run = 0;
        for (int i = 0; i < NB_SCAN; ++i) { int t = blockSums[i]; blockSums[i] = run; run += t; }
    }
}

__global__ __launch_bounds__(1024) void scan_kernel(const int* __restrict__ cnt,
                                                    const int* __restrict__ blockSums,
                                                    int* __restrict__ row_start) {
    __shared__ int s[1024];
    int i = blockIdx.x * 1024 + threadIdx.x;
    int v = (i < N_NODES) ? cnt[i] : 0;
    s[threadIdx.x] = v;
    __syncthreads();
    for (int off = 1; off < 1024; off <<= 1) {
        int t = (threadIdx.x >= off) ? s[threadIdx.x - off] : 0;
        __syncthreads();
        s[threadIdx.x] += t;
        __syncthreads();
    }
    if (i < N_NODES) row_start[i] = blockSums[blockIdx.x] + s[threadIdx.x] - v;  // exclusive
}

// ---------------- fill CSR: packed (src, norm); norm fused from cnt ----------------

__global__ void fill_kernel(const int* __restrict__ src, const int* __restrict__ dst,
                            const int* __restrict__ cnt, const int* __restrict__ row_start,
                            int* __restrict__ cursor, int2* __restrict__ csr) {
    int e = blockIdx.x * 256 + threadIdx.x;
    if (e >= N_EDGES) return;
    int s = src[e], d = dst[e];
    int pos = row_start[d] + atomicAdd(&cursor[d], 1);
    int cs = cnt[s];
    float dis = (cs > 0) ? rsqrtf((float)cs) : 0.0f;
    float did = rsqrtf((float)cnt[d]);          // cnt[d] >= 1: edge e targets d
    csr[pos] = make_int2(s, __float_as_int(dis * did));
}

// ---------------- GEMM1: h1 = x @ W1   [50000x128] = [50000x128]@[128x128] ----------------
// W in LDS (b128 reads only); x read from global (row-broadcast across lanes -> L1).
// 32 rows/block; thread = 4 rows x 4 cols.

__global__ __launch_bounds__(256) void gemm1_kernel(const float* __restrict__ x,
                                                    const float* __restrict__ W,
                                                    float* __restrict__ h) {
    __shared__ float Wds[128 * 128];   // 64 KB -> 2 blocks/CU
    float4* Wds4 = (float4*)Wds;
    const float4* W4 = (const float4*)W;
#pragma unroll
    for (int i = threadIdx.x; i < 4096; i += 256) Wds4[i] = W4[i];
    __syncthreads();

    int tx = threadIdx.x & 31;        // col4 0..31
    int ty = threadIdx.x >> 5;        // 8 groups of 4 rows
    int row0 = blockIdx.x * 32 + ty * 4;

    const float4* xr[4];
    bool valid[4];
#pragma unroll
    for (int i = 0; i < 4; ++i) {
        int r = row0 + i;
        valid[i] = (r < N_NODES);
        xr[i] = (const float4*)(x + (size_t)(valid[i] ? r : 0) * 128);
    }

    float4 acc[4] = {};
#pragma unroll 2
    for (int k4 = 0; k4 < 32; ++k4) {
        float4 xv[4];
#pragma unroll
        for (int i = 0; i < 4; ++i) xv[i] = xr[i][k4];
#pragma unroll
        for (int kk = 0; kk < 4; ++kk) {
            float4 w = Wds4[(k4 * 4 + kk) * 32 + tx];
#pragma unroll
            for (int i = 0; i < 4; ++i) {
                float xs = ((const float*)&xv[i])[kk];
                acc[i].x += xs * w.x;
                acc[i].y += xs * w.y;
                acc[i].z += xs * w.z;
                acc[i].w += xs * w.w;
            }
        }
    }

#pragma unroll
    for (int i = 0; i < 4; ++i)
        if (valid[i]) ((float4*)(h + (size_t)(row0 + i) * 128))[tx] = acc[i];
}

// ---------------- agg1: a1[n] = relu(b1 + sum norm_e * h1[src_e])  [128 ch] ----------
// 1 wave/node; 4 groups of 16 lanes; lane holds 2 float4 (slots q, q+16); unroll 2
// -> 8 edges / 16 gathers in flight per wave.

__global__ __launch_bounds__(256) void agg1_kernel(const int2* __restrict__ csr,
                                                   const int* __restrict__ row_start,
                                                   const int* __restrict__ cnt,
                                                   const float* __restrict__ b1,
                                                   const float* __restrict__ h1,
                                                   float* __restrict__ a1) {
    int node = blockIdx.x * 4 + (threadIdx.x >> 6);
    if (node >= N_NODES) return;
    int lane = threadIdx.x & 63;
    int grp = lane >> 4;         // 4 groups: edge j = grp + 4t
    int q   = lane & 15;         // float4 slots q and q+16 (of 32)
    int start = row_start[node];
    int m = cnt[node];

    float4 accA = make_float4(0.f, 0.f, 0.f, 0.f);
    float4 accB = make_float4(0.f, 0.f, 0.f, 0.f);

    int j = grp;
    for (; j + 4 < m; j += 8) {
        int2 p0 = csr[start + j];
        int2 p1 = csr[start + j + 4];
        const float4* r0 = (const float4*)(h1 + (size_t)p0.x * 128);
        const float4* r1 = (const float4*)(h1 + (size_t)p1.x * 128);
        float4 v0a = r0[q], v0b = r0[q + 16];
        float4 v1a = r1[q], v1b = r1[q + 16];
        float n0 = __int_as_float(p0.y), n1 = __int_as_float(p1.y);
        accA.x += v0a.x * n0; accA.y += v0a.y * n0; accA.z += v0a.z * n0; accA.w += v0a.w * n0;
        accB.x += v0b.x * n0; accB.y += v0b.y * n0; accB.z += v0b.z * n0; accB.w += v0b.w * n0;
        accA.x += v1a.x * n1; accA.y += v1a.y * n1; accA.z += v1a.z * n1; accA.w += v1a.w * n1;
        accB.x += v1b.x * n1; accB.y += v1b.y * n1; accB.z += v1b.z * n1; accB.w += v1b.w * n1;
    }
    if (j < m) {
        int2 p0 = csr[start + j];
        const float4* r0 = (const float4*)(h1 + (size_t)p0.x * 128);
        float4 v0a = r0[q], v0b = r0[q + 16];
        float n0 = __int_as_float(p0.y);
        accA.x += v0a.x * n0; accA.y += v0a.y * n0; accA.z += v0a.z * n0; accA.w += v0a.w * n0;
        accB.x += v0b.x * n0; accB.y += v0b.y * n0; accB.z += v0b.z * n0; accB.w += v0b.w * n0;
    }

    // reduce across 4 groups (lanes differing in bits 4,5)
#pragma unroll
    for (int d = 16; d <= 32; d <<= 1) {
        accA.x += __shfl_xor(accA.x, d, 64);
        accA.y += __shfl_xor(accA.y, d, 64);
        accA.z += __shfl_xor(accA.z, d, 64);
        accA.w += __shfl_xor(accA.w, d, 64);
        accB.x += __shfl_xor(accB.x, d, 64);
        accB.y += __shfl_xor(accB.y, d, 64);
        accB.z += __shfl_xor(accB.z, d, 64);
        accB.w += __shfl_xor(accB.w, d, 64);
    }

    if (lane < 16) {
        float4 bA = ((const float4*)b1)[q];
        float4 bB = ((const float4*)b1)[q + 16];
        float4 rA, rB;
        rA.x = fmaxf(accA.x + bA.x, 0.f); rA.y = fmaxf(accA.y + bA.y, 0.f);
        rA.z = fmaxf(accA.z + bA.z, 0.f); rA.w = fmaxf(accA.w + bA.w, 0.f);
        rB.x = fmaxf(accB.x + bB.x, 0.f); rB.y = fmaxf(accB.y + bB.y, 0.f);
        rB.z = fmaxf(accB.z + bB.z, 0.f); rB.w = fmaxf(accB.w + bB.w, 0.f);
        float4* o = (float4*)(a1 + (size_t)node * 128);
        o[q] = rA;
        o[q + 16] = rB;
    }
}

// ---------------- GEMM2: h2 = a1 @ W2   [50000x64] = [50000x128]@[128x64] ----------------
// W2 in LDS (32 KB); a1 from global. 64 rows/block; thread = 4 rows x 4 cols.

__global__ __launch_bounds__(256) void gemm2_kernel(const float* __restrict__ a1,
                                                    const float* __restrict__ W,
                                                    float* __restrict__ h2) {
    __shared__ float Wds[128 * 64];    // 32 KB
    float4* Wds4 = (float4*)Wds;
    const float4* W4 = (const float4*)W;
#pragma unroll
    for (int i = threadIdx.x; i < 2048; i += 256) Wds4[i] = W4[i];
    __syncthreads();

    int tx = threadIdx.x & 15;        // col4 0..15
    int ty = threadIdx.x >> 4;        // 16 groups of 4 rows
    int row0 = blockIdx.x * 64 + ty * 4;

    const float4* xr[4];
    bool valid[4];
#pragma unroll
    for (int i = 0; i < 4; ++i) {
        int r = row0 + i;
        valid[i] = (r < N_NODES);
        xr[i] = (const float4*)(a1 + (size_t)(valid[i] ? r : 0) * 128);
    }

    float4 acc[4] = {};
#pragma unroll 2
    for (int k4 = 0; k4 < 32; ++k4) {
        float4 xv[4];
#pragma unroll
        for (int i = 0; i < 4; ++i) xv[i] = xr[i][k4];
#pragma unroll
        for (int kk = 0; kk < 4; ++kk) {
            float4 w = Wds4[(k4 * 4 + kk) * 16 + tx];
#pragma unroll
            for (int i = 0; i < 4; ++i) {
                float xs = ((const float*)&xv[i])[kk];
                acc[i].x += xs * w.x;
                acc[i].y += xs * w.y;
                acc[i].z += xs * w.z;
                acc[i].w += xs * w.w;
            }
        }
    }

#pragma unroll
    for (int i = 0; i < 4; ++i)
        if (valid[i]) ((float4*)(h2 + (size_t)(row0 + i) * 64))[tx] = acc[i];
}

// ---------------- agg2: out[n] = b2 + sum norm_e * h2[src_e]  [64 ch] ----------
// 1 wave/node; 8 groups of 8 lanes; lane holds 2 float4 (slots q, q+8); unroll 2
// -> 16 edges / 32 gathers in flight per wave.

__global__ __launch_bounds__(256) void agg2_kernel(const int2* __restrict__ csr,
                                                   const int* __restrict__ row_start,
                                                   const int* __restrict__ cnt,
                                                   const float* __restrict__ b2,
                                                   const float* __restrict__ h2,
                                                   float* __restrict__ out) {
    int node = blockIdx.x * 4 + (threadIdx.x >> 6);
    if (node >= N_NODES) return;
    int lane = threadIdx.x & 63;
    int grp = lane >> 3;         // 8 groups: edge j = grp + 8t
    int q   = lane & 7;          // float4 slots q and q+8 (of 16)
    int start = row_start[node];
    int m = cnt[node];

    float4 accA = make_float4(0.f, 0.f, 0.f, 0.f);
    float4 accB = make_float4(0.f, 0.f, 0.f, 0.f);

    int j = grp;
    for (; j + 8 < m; j += 16) {
        int2 p0 = csr[start + j];
        int2 p1 = csr[start + j + 8];
        const float4* r0 = (const float4*)(h2 + (size_t)p0.x * 64);
        const float4* r1 = (const float4*)(h2 + (size_t)p1.x * 64);
        float4 v0a = r0[q], v0b = r0[q + 8];
        float4 v1a = r1[q], v1b = r1[q + 8];
        float n0 = __int_as_float(p0.y), n1 = __int_as_float(p1.y);
        accA.x += v0a.x * n0; accA.y += v0a.y * n0; accA.z += v0a.z * n0; accA.w += v0a.w * n0;
        accB.x += v0b.x * n0; accB.y += v0b.y * n0; accB.z += v0b.z * n0; accB.w += v0b.w * n0;
        accA.x += v1a.x * n1; accA.y += v1a.y * n1; accA.z += v1a.z * n1; accA.w += v1a.w * n1;
        accB.x += v1b.x * n1; accB.y += v1b.y * n1; accB.z += v1b.z * n1; accB.w += v1b.w * n1;
    }
    if (j < m) {
        int2 p0 = csr[start + j];
        const float4* r0 = (const float4*)(h2 + (size_t)p0.x * 64);
        float4 v0a = r0[q], v0b = r0[q + 8];
        float n0 = __int_as_float(p0.y);
        accA.x += v0a.x * n0; accA.y += v0a.y * n0; accA.z += v0a.z * n0; accA.w += v0a.w * n0;
        accB.x += v0b.x * n0; accB.y += v0b.y * n0; accB.z += v0b.z * n0; accB.w += v0b.w * n0;
    }

    // reduce across 8 groups (lanes differing in bits 3,4,5)
#pragma unroll
    for (int d = 8; d <= 32; d <<= 1) {
        accA.x += __shfl_xor(accA.x, d, 64);
        accA.y += __shfl_xor(accA.y, d, 64);
        accA.z += __shfl_xor(accA.z, d, 64);
        accA.w += __shfl_xor(accA.w, d, 64);
        accB.x += __shfl_xor(accB.x, d, 64);
        accB.y += __shfl_xor(accB.y, d, 64);
        accB.z += __shfl_xor(accB.z, d, 64);
        accB.w += __shfl_xor(accB.w, d, 64);
    }

    if (lane < 8) {
        float4 bA = ((const float4*)b2)[q];
        float4 bB = ((const float4*)b2)[q + 8];
        float4* o = (float4*)(out + (size_t)node * 64);
        float4 rA, rB;
        rA.x = accA.x + bA.x; rA.y = accA.y + bA.y; rA.z = accA.z + bA.z; rA.w = accA.w + bA.w;
        rB.x = accB.x + bB.x; rB.y = accB.y + bB.y; rB.z = accB.z + bB.z; rB.w = accB.w + bB.w;
        o[q] = rA;
        o[q + 8] = rB;
    }
}

// ---------------- launch ----------------

extern "C" void kernel_launch(void* const* d_in, const int* in_sizes, int n_in,
                              void* d_out, int out_size, void* d_ws, size_t ws_size,
                              hipStream_t stream) {
    const float* x  = (const float*)d_in[0];
    const int*   ei = (const int*)d_in[1];       // [2, E]: src = ei[0..E), dst = ei[E..2E)
    const float* W1 = (const float*)d_in[2];
    const float* b1 = (const float*)d_in[3];
    const float* W2 = (const float*)d_in[4];
    const float* b2 = (const float*)d_in[5];
    float* out = (float*)d_out;

    const int* src = ei;
    const int* dst = ei + N_EDGES;

    // workspace layout (32-bit words)
    char* ws = (char*)d_ws;
    int*   cnt       = (int*)ws;                              // NPAD
    int*   cursor    = cnt + NPAD;                            // NPAD  (adjacent -> one memset)
    int*   row_start = cursor + NPAD;                         // NPAD
    int*   blockSums = row_start + NPAD;                      // 64
    int2*  csr       = (int2*)(blockSums + 64);               // N_EDGES int2 (8B aligned)
    float* h1        = (float*)(csr + N_EDGES);               // 50000*128 (h2 aliases h1)
    float* a1        = h1 + (size_t)N_NODES * HID_DIM;        // 50000*128
    float* h2        = h1;                                    // reuse: h1 dead after agg1

    // 1. zero cnt+cursor, histogram dst
    hipMemsetAsync(cnt, 0, 2 * NPAD * sizeof(int), stream);
    hist_kernel<<<(N_EDGES + 255) / 256, 256, 0, stream>>>(dst, cnt);

    // 2. exclusive scan cnt -> row_start
    reduce_kernel<<<NB_SCAN, 1024, 0, stream>>>(cnt, blockSums);
    scan_sums_kernel<<<1, 64, 0, stream>>>(blockSums);
    scan_kernel<<<NB_SCAN, 1024, 0, stream>>>(cnt, blockSums, row_start);

    // 3. fill CSR (packed src, norm) — norm fused from cnt
    fill_kernel<<<(N_EDGES + 255) / 256, 256, 0, stream>>>(src, dst, cnt, row_start,
                                                           cursor, csr);

    // 4. h1 = x @ W1
    gemm1_kernel<<<(N_NODES + 31) / 32, 256, 0, stream>>>(x, W1, h1);

    // 5. a1 = relu(b1 + gather-sum)
    agg1_kernel<<<(N_NODES + 3) / 4, 256, 0, stream>>>(csr, row_start, cnt, b1, h1, a1);

    // 6. h2 = a1 @ W2
    gemm2_kernel<<<(N_NODES + 63) / 64, 256, 0, stream>>>(a1, W2, h2);

    // 7. out = b2 + gather-sum
    agg2_kernel<<<(N_NODES + 3) / 4, 256, 0, stream>>>(csr, row_start, cnt, b2, h2, out);
}

// Round 5
// 278.839 us; speedup vs baseline: 7.9212x; 1.1109x over previous
//
#include <hip/hip_runtime.h>

#define N_NODES 50000
#define N_EDGES 800000
#define IN_DIM  128
#define HID_DIM 128
#define OUT_DIM 64

#define NPAD 50176                          // N_NODES rounded up (alignment)
#define NB_SCAN ((N_NODES + 1023) / 1024)   // 49

// float -> bf16 (round-to-nearest-even), as ushort
__device__ __forceinline__ unsigned short f2bf(float f) {
    unsigned u = __float_as_uint(f);
    u += 0x7fffu + ((u >> 16) & 1u);
    return (unsigned short)(u >> 16);
}
// bf16 pair unpack from a uint (little-endian: low ushort first)
__device__ __forceinline__ float bflo(unsigned u) { return __uint_as_float(u << 16); }
__device__ __forceinline__ float bfhi(unsigned u) { return __uint_as_float(u & 0xffff0000u); }

// ---------------- CSR build: histogram of dst ----------------

__global__ void hist_kernel(const int* __restrict__ dst, int* __restrict__ cnt) {
    int e = blockIdx.x * 256 + threadIdx.x;
    if (e < N_EDGES) atomicAdd(&cnt[dst[e]], 1);
}

__global__ void dinv_kernel(const int* __restrict__ cnt, float* __restrict__ dinv) {
    int n = blockIdx.x * 256 + threadIdx.x;
    if (n < N_NODES) {
        int d = cnt[n];
        dinv[n] = (d > 0) ? rsqrtf((float)d) : 0.0f;
    }
}

// ---------------- exclusive scan of cnt -> row_start ----------------

__global__ __launch_bounds__(1024) void reduce_kernel(const int* __restrict__ cnt,
                                                      int* __restrict__ blockSums) {
    __shared__ int s[1024];
    int i = blockIdx.x * 1024 + threadIdx.x;
    s[threadIdx.x] = (i < N_NODES) ? cnt[i] : 0;
    __syncthreads();
    for (int off = 512; off > 0; off >>= 1) {
        if (threadIdx.x < off) s[threadIdx.x] += s[threadIdx.x + off];
        __syncthreads();
    }
    if (threadIdx.x == 0) blockSums[blockIdx.x] = s[0];
}

__global__ void scan_sums_kernel(int* __restrict__ blockSums) {
    if (threadIdx.x == 0) {
        int run = 0;
        for (int i = 0; i < NB_SCAN; ++i) { int t = blockSums[i]; blockSums[i] = run; run += t; }
    }
}

__global__ __launch_bounds__(1024) void scan_kernel(const int* __restrict__ cnt,
                                                    const int* __restrict__ blockSums,
                                                    int* __restrict__ row_start) {
    __shared__ int s[1024];
    int i = blockIdx.x * 1024 + threadIdx.x;
    int v = (i < N_NODES) ? cnt[i] : 0;
    s[threadIdx.x] = v;
    __syncthreads();
    for (int off = 1; off < 1024; off <<= 1) {
        int t = (threadIdx.x >= off) ? s[threadIdx.x - off] : 0;
        __syncthreads();
        s[threadIdx.x] += t;
        __syncthreads();
    }
    if (i < N_NODES) row_start[i] = blockSums[blockIdx.x] + s[threadIdx.x] - v;  // exclusive
}

// ---------------- fill CSR: src only (norm factorized out) ----------------

__global__ void fill_kernel(const int* __restrict__ src, const int* __restrict__ dst,
                            const int* __restrict__ row_start,
                            int* __restrict__ cursor, int* __restrict__ csr_src) {
    int e = blockIdx.x * 256 + threadIdx.x;
    if (e >= N_EDGES) return;
    int s = src[e], d = dst[e];
    int pos = row_start[d] + atomicAdd(&cursor[d], 1);
    csr_src[pos] = s;
}

// ---------------- GEMM1: h1b = bf16( dinv[row] * (x @ W1) )  [50000x128] ----------------
// Column-split: grid.y in {0,1}, 64 cols/block -> 32 KB LDS -> 4-5 blocks/CU.
// 64 rows x 64 cols per block; thread = 4 rows x 4 cols.

__global__ __launch_bounds__(256) void gemm1_kernel(const float* __restrict__ x,
                                                    const float* __restrict__ W,
                                                    const float* __restrict__ dinv,
                                                    unsigned short* __restrict__ h1b) {
    __shared__ float Wds[128 * 64];    // 32 KB
    int c0 = blockIdx.y * 64;          // column offset
    float4* Wds4 = (float4*)Wds;
    const float4* W4 = (const float4*)W;
    int cb4 = c0 >> 2;                 // 0 or 16
#pragma unroll
    for (int i = threadIdx.x; i < 128 * 16; i += 256) {
        int k = i >> 4, c4 = i & 15;
        Wds4[i] = W4[k * 32 + cb4 + c4];
    }
    __syncthreads();

    int tx = threadIdx.x & 15;        // col4 within the 64-col half
    int ty = threadIdx.x >> 4;        // 16 groups of 4 rows
    int row0 = blockIdx.x * 64 + ty * 4;

    const float4* xr[4];
    bool valid[4];
#pragma unroll
    for (int i = 0; i < 4; ++i) {
        int r = row0 + i;
        valid[i] = (r < N_NODES);
        xr[i] = (const float4*)(x + (size_t)(valid[i] ? r : 0) * 128);
    }

    float4 acc[4] = {};
#pragma unroll 2
    for (int k4 = 0; k4 < 32; ++k4) {
        float4 xv[4];
#pragma unroll
        for (int i = 0; i < 4; ++i) xv[i] = xr[i][k4];
#pragma unroll
        for (int kk = 0; kk < 4; ++kk) {
            float4 w = Wds4[(k4 * 4 + kk) * 16 + tx];
#pragma unroll
            for (int i = 0; i < 4; ++i) {
                float xs = ((const float*)&xv[i])[kk];
                acc[i].x += xs * w.x;
                acc[i].y += xs * w.y;
                acc[i].z += xs * w.z;
                acc[i].w += xs * w.w;
            }
        }
    }

#pragma unroll
    for (int i = 0; i < 4; ++i) {
        if (valid[i]) {
            int row = row0 + i;
            float dn = dinv[row];
            ushort4 o;
            o.x = f2bf(acc[i].x * dn);
            o.y = f2bf(acc[i].y * dn);
            o.z = f2bf(acc[i].z * dn);
            o.w = f2bf(acc[i].w * dn);
            *(ushort4*)(h1b + (size_t)row * 128 + c0 + tx * 4) = o;
        }
    }
}

// ---------------- agg1: a1[n] = relu(b1 + dinv[n] * sum h1b[src_e])  [128 ch bf16 rows] ----
// 1 wave/node; 4 groups of 16 lanes; lane loads one uint4 (8 bf16 ch); unroll 2
// -> 8 edges in flight per wave.

__global__ __launch_bounds__(256) void agg1_kernel(const int* __restrict__ csr_src,
                                                   const int* __restrict__ row_start,
                                                   const int* __restrict__ cnt,
                                                   const float* __restrict__ dinv,
                                                   const float* __restrict__ b1,
                                                   const unsigned short* __restrict__ h1b,
                                                   float* __restrict__ a1) {
    int node = blockIdx.x * 4 + (threadIdx.x >> 6);
    if (node >= N_NODES) return;
    int lane = threadIdx.x & 63;
    int grp = lane >> 4;         // 4 groups: edge j = grp + 4t
    int q   = lane & 15;         // uint4 slot (channels 8q..8q+7)
    int start = row_start[node];
    int m = cnt[node];

    float acc[8] = {};

    int j = grp;
    for (; j + 4 < m; j += 8) {
        int s0 = csr_src[start + j];
        int s1 = csr_src[start + j + 4];
        uint4 u0 = ((const uint4*)(h1b + (size_t)s0 * 128))[q];
        uint4 u1 = ((const uint4*)(h1b + (size_t)s1 * 128))[q];
        acc[0] += bflo(u0.x); acc[1] += bfhi(u0.x);
        acc[2] += bflo(u0.y); acc[3] += bfhi(u0.y);
        acc[4] += bflo(u0.z); acc[5] += bfhi(u0.z);
        acc[6] += bflo(u0.w); acc[7] += bfhi(u0.w);
        acc[0] += bflo(u1.x); acc[1] += bfhi(u1.x);
        acc[2] += bflo(u1.y); acc[3] += bfhi(u1.y);
        acc[4] += bflo(u1.z); acc[5] += bfhi(u1.z);
        acc[6] += bflo(u1.w); acc[7] += bfhi(u1.w);
    }
    if (j < m) {
        int s0 = csr_src[start + j];
        uint4 u0 = ((const uint4*)(h1b + (size_t)s0 * 128))[q];
        acc[0] += bflo(u0.x); acc[1] += bfhi(u0.x);
        acc[2] += bflo(u0.y); acc[3] += bfhi(u0.y);
        acc[4] += bflo(u0.z); acc[5] += bfhi(u0.z);
        acc[6] += bflo(u0.w); acc[7] += bfhi(u0.w);
    }

    // reduce across 4 groups (lane bits 4,5)
#pragma unroll
    for (int d = 16; d <= 32; d <<= 1) {
#pragma unroll
        for (int c = 0; c < 8; ++c) acc[c] += __shfl_xor(acc[c], d, 64);
    }

    if (lane < 16) {
        float dn = dinv[node];
        float4 bA = ((const float4*)b1)[2 * q];
        float4 bB = ((const float4*)b1)[2 * q + 1];
        float4 rA, rB;
        rA.x = fmaxf(acc[0] * dn + bA.x, 0.f);
        rA.y = fmaxf(acc[1] * dn + bA.y, 0.f);
        rA.z = fmaxf(acc[2] * dn + bA.z, 0.f);
        rA.w = fmaxf(acc[3] * dn + bA.w, 0.f);
        rB.x = fmaxf(acc[4] * dn + bB.x, 0.f);
        rB.y = fmaxf(acc[5] * dn + bB.y, 0.f);
        rB.z = fmaxf(acc[6] * dn + bB.z, 0.f);
        rB.w = fmaxf(acc[7] * dn + bB.w, 0.f);
        float4* o = (float4*)(a1 + (size_t)node * 128);
        o[2 * q] = rA;
        o[2 * q + 1] = rB;
    }
}

// ---------------- GEMM2: h2b = bf16( dinv[row] * (a1 @ W2) )  [50000x64] ----------------
// 64 rows x 64 cols per block; W2 fully in LDS (32 KB).

__global__ __launch_bounds__(256) void gemm2_kernel(const float* __restrict__ a1,
                                                    const float* __restrict__ W,
                                                    const float* __restrict__ dinv,
                                                    unsigned short* __restrict__ h2b) {
    __shared__ float Wds[128 * 64];    // 32 KB
    float4* Wds4 = (float4*)Wds;
    const float4* W4 = (const float4*)W;
#pragma unroll
    for (int i = threadIdx.x; i < 2048; i += 256) Wds4[i] = W4[i];
    __syncthreads();

    int tx = threadIdx.x & 15;        // col4 0..15
    int ty = threadIdx.x >> 4;        // 16 groups of 4 rows
    int row0 = blockIdx.x * 64 + ty * 4;

    const float4* xr[4];
    bool valid[4];
#pragma unroll
    for (int i = 0; i < 4; ++i) {
        int r = row0 + i;
        valid[i] = (r < N_NODES);
        xr[i] = (const float4*)(a1 + (size_t)(valid[i] ? r : 0) * 128);
    }

    float4 acc[4] = {};
#pragma unroll 2
    for (int k4 = 0; k4 < 32; ++k4) {
        float4 xv[4];
#pragma unroll
        for (int i = 0; i < 4; ++i) xv[i] = xr[i][k4];
#pragma unroll
        for (int kk = 0; kk < 4; ++kk) {
            float4 w = Wds4[(k4 * 4 + kk) * 16 + tx];
#pragma unroll
            for (int i = 0; i < 4; ++i) {
                float xs = ((const float*)&xv[i])[kk];
                acc[i].x += xs * w.x;
                acc[i].y += xs * w.y;
                acc[i].z += xs * w.z;
                acc[i].w += xs * w.w;
            }
        }
    }

#pragma unroll
    for (int i = 0; i < 4; ++i) {
        if (valid[i]) {
            int row = row0 + i;
            float dn = dinv[row];
            ushort4 o;
            o.x = f2bf(acc[i].x * dn);
            o.y = f2bf(acc[i].y * dn);
            o.z = f2bf(acc[i].z * dn);
            o.w = f2bf(acc[i].w * dn);
            *(ushort4*)(h2b + (size_t)row * 64 + tx * 4) = o;
        }
    }
}

// ---------------- agg2: out[n] = b2 + dinv[n] * sum h2b[src_e]  [64 ch bf16 rows] ----------
// 1 wave/node; 8 groups of 8 lanes; lane loads one uint4 (8 bf16 ch); unroll 2
// -> 16 edges in flight per wave.

__global__ __launch_bounds__(256) void agg2_kernel(const int* __restrict__ csr_src,
                                                   const int* __restrict__ row_start,
                                                   const int* __restrict__ cnt,
                                                   const float* __restrict__ dinv,
                                                   const float* __restrict__ b2,
                                                   const unsigned short* __restrict__ h2b,
                                                   float* __restrict__ out) {
    int node = blockIdx.x * 4 + (threadIdx.x >> 6);
    if (node >= N_NODES) return;
    int lane = threadIdx.x & 63;
    int grp = lane >> 3;         // 8 groups: edge j = grp + 8t
    int q   = lane & 7;          // uint4 slot (channels 8q..8q+7)
    int start = row_start[node];
    int m = cnt[node];

    float acc[8] = {};

    int j = grp;
    for (; j + 8 < m; j += 16) {
        int s0 = csr_src[start + j];
        int s1 = csr_src[start + j + 8];
        uint4 u0 = ((const uint4*)(h2b + (size_t)s0 * 64))[q];
        uint4 u1 = ((const uint4*)(h2b + (size_t)s1 * 64))[q];
        acc[0] += bflo(u0.x); acc[1] += bfhi(u0.x);
        acc[2] += bflo(u0.y); acc[3] += bfhi(u0.y);
        acc[4] += bflo(u0.z); acc[5] += bfhi(u0.z);
        acc[6] += bflo(u0.w); acc[7] += bfhi(u0.w);
        acc[0] += bflo(u1.x); acc[1] += bfhi(u1.x);
        acc[2] += bflo(u1.y); acc[3] += bfhi(u1.y);
        acc[4] += bflo(u1.z); acc[5] += bfhi(u1.z);
        acc[6] += bflo(u1.w); acc[7] += bfhi(u1.w);
    }
    if (j < m) {
        int s0 = csr_src[start + j];
        uint4 u0 = ((const uint4*)(h2b + (size_t)s0 * 64))[q];
        acc[0] += bflo(u0.x); acc[1] += bfhi(u0.x);
        acc[2] += bflo(u0.y); acc[3] += bfhi(u0.y);
        acc[4] += bflo(u0.z); acc[5] += bfhi(u0.z);
        acc[6] += bflo(u0.w); acc[7] += bfhi(u0.w);
    }

    // reduce across 8 groups (lane bits 3,4,5)
#pragma unroll
    for (int d = 8; d <= 32; d <<= 1) {
#pragma unroll
        for (int c = 0; c < 8; ++c) acc[c] += __shfl_xor(acc[c], d, 64);
    }

    if (lane < 8) {
        float dn = dinv[node];
        float4 bA = ((const float4*)b2)[2 * q];
        float4 bB = ((const float4*)b2)[2 * q + 1];
        float4 rA, rB;
        rA.x = acc[0] * dn + bA.x;
        rA.y = acc[1] * dn + bA.y;
        rA.z = acc[2] * dn + bA.z;
        rA.w = acc[3] * dn + bA.w;
        rB.x = acc[4] * dn + bB.x;
        rB.y = acc[5] * dn + bB.y;
        rB.z = acc[6] * dn + bB.z;
        rB.w = acc[7] * dn + bB.w;
        float4* o = (float4*)(out + (size_t)node * 64);
        o[2 * q] = rA;
        o[2 * q + 1] = rB;
    }
}

// ---------------- launch ----------------

extern "C" void kernel_launch(void* const* d_in, const int* in_sizes, int n_in,
                              void* d_out, int out_size, void* d_ws, size_t ws_size,
                              hipStream_t stream) {
    const float* x  = (const float*)d_in[0];
    const int*   ei = (const int*)d_in[1];       // [2, E]: src = ei[0..E), dst = ei[E..2E)
    const float* W1 = (const float*)d_in[2];
    const float* b1 = (const float*)d_in[3];
    const float* W2 = (const float*)d_in[4];
    const float* b2 = (const float*)d_in[5];
    float* out = (float*)d_out;

    const int* src = ei;
    const int* dst = ei + N_EDGES;

    // workspace layout (32-bit words)
    char* ws = (char*)d_ws;
    int*   cnt       = (int*)ws;                              // NPAD
    int*   cursor    = cnt + NPAD;                            // NPAD  (adjacent -> one memset)
    int*   row_start = cursor + NPAD;                         // NPAD
    int*   blockSums = row_start + NPAD;                      // 64
    float* dinv      = (float*)(blockSums + 64);              // NPAD
    int*   csr_src   = (int*)(dinv + NPAD);                   // N_EDGES
    unsigned short* h1b = (unsigned short*)(csr_src + N_EDGES); // 50000*128 bf16 (h2b aliases)
    float* a1        = (float*)(h1b + (size_t)N_NODES * HID_DIM); // 50000*128 fp32
    unsigned short* h2b = h1b;                                // reuse: h1b dead after agg1

    // 1. zero cnt+cursor, histogram dst, dinv
    hipMemsetAsync(cnt, 0, 2 * NPAD * sizeof(int), stream);
    hist_kernel<<<(N_EDGES + 255) / 256, 256, 0, stream>>>(dst, cnt);
    dinv_kernel<<<(N_NODES + 255) / 256, 256, 0, stream>>>(cnt, dinv);

    // 2. exclusive scan cnt -> row_start
    reduce_kernel<<<NB_SCAN, 1024, 0, stream>>>(cnt, blockSums);
    scan_sums_kernel<<<1, 64, 0, stream>>>(blockSums);
    scan_kernel<<<NB_SCAN, 1024, 0, stream>>>(cnt, blockSums, row_start);

    // 3. fill CSR (src only)
    fill_kernel<<<(N_EDGES + 255) / 256, 256, 0, stream>>>(src, dst, row_start, cursor, csr_src);

    // 4. h1b = bf16(dinv * (x @ W1))
    {
        dim3 g((N_NODES + 63) / 64, 2);
        gemm1_kernel<<<g, 256, 0, stream>>>(x, W1, dinv, h1b);
    }

    // 5. a1 = relu(b1 + dinv * gather-sum)
    agg1_kernel<<<(N_NODES + 3) / 4, 256, 0, stream>>>(csr_src, row_start, cnt, dinv, b1, h1b, a1);

    // 6. h2b = bf16(dinv * (a1 @ W2))
    gemm2_kernel<<<(N_NODES + 63) / 64, 256, 0, stream>>>(a1, W2, dinv, h2b);

    // 7. out = b2 + dinv * gather-sum
    agg2_kernel<<<(N_NODES + 3) / 4, 256, 0, stream>>>(csr_src, row_start, cnt, dinv, b2, h2b, out);
}

// Round 6
// 247.934 us; speedup vs baseline: 8.9085x; 1.1246x over previous
//
#include <hip/hip_runtime.h>

#define N_NODES 50000
#define N_EDGES 800000
#define IN_DIM  128
#define HID_DIM 128
#define OUT_DIM 64

#define NPAD 50176                          // N_NODES rounded up (alignment)
#define NB_SCAN ((N_NODES + 1023) / 1024)   // 49

// float -> bf16 (round-to-nearest-even), as ushort
__device__ __forceinline__ unsigned short f2bf(float f) {
    unsigned u = __float_as_uint(f);
    u += 0x7fffu + ((u >> 16) & 1u);
    return (unsigned short)(u >> 16);
}
// bf16 pair unpack from a uint (little-endian: low ushort first)
__device__ __forceinline__ float bflo(unsigned u) { return __uint_as_float(u << 16); }
__device__ __forceinline__ float bfhi(unsigned u) { return __uint_as_float(u & 0xffff0000u); }

// ---------------- rank+histogram: rank[e] = old count of dst[e] ----------------
// 4 edges/thread; the atomic return value IS the within-node rank, making the
// later fill pass atomic-free.

__global__ void rank_hist_kernel(const int* __restrict__ dst, int* __restrict__ cnt,
                                 int* __restrict__ rank) {
    int e = (blockIdx.x * 256 + threadIdx.x) * 4;
    if (e >= N_EDGES) return;                 // N_EDGES % 4 == 0 -> full int4 safe
    int4 d4 = *(const int4*)(dst + e);
    int r0 = atomicAdd(&cnt[d4.x], 1);
    int r1 = atomicAdd(&cnt[d4.y], 1);
    int r2 = atomicAdd(&cnt[d4.z], 1);
    int r3 = atomicAdd(&cnt[d4.w], 1);
    *(int4*)(rank + e) = make_int4(r0, r1, r2, r3);
}

// ---------------- exclusive scan of cnt -> row_start (+ fused dinv) ----------------

__global__ __launch_bounds__(1024) void reduce_kernel(const int* __restrict__ cnt,
                                                      int* __restrict__ blockSums) {
    __shared__ int s[1024];
    int i = blockIdx.x * 1024 + threadIdx.x;
    s[threadIdx.x] = (i < N_NODES) ? cnt[i] : 0;
    __syncthreads();
    for (int off = 512; off > 0; off >>= 1) {
        if (threadIdx.x < off) s[threadIdx.x] += s[threadIdx.x + off];
        __syncthreads();
    }
    if (threadIdx.x == 0) blockSums[blockIdx.x] = s[0];
}

__global__ void scan_sums_kernel(int* __restrict__ blockSums) {
    if (threadIdx.x == 0) {
        int run = 0;
        for (int i = 0; i < NB_SCAN; ++i) { int t = blockSums[i]; blockSums[i] = run; run += t; }
    }
}

__global__ __launch_bounds__(1024) void scan_kernel(const int* __restrict__ cnt,
                                                    const int* __restrict__ blockSums,
                                                    int* __restrict__ row_start,
                                                    float* __restrict__ dinv) {
    __shared__ int s[1024];
    int i = blockIdx.x * 1024 + threadIdx.x;
    int v = (i < N_NODES) ? cnt[i] : 0;
    s[threadIdx.x] = v;
    __syncthreads();
    for (int off = 1; off < 1024; off <<= 1) {
        int t = (threadIdx.x >= off) ? s[threadIdx.x - off] : 0;
        __syncthreads();
        s[threadIdx.x] += t;
        __syncthreads();
    }
    if (i < N_NODES) {
        row_start[i] = blockSums[blockIdx.x] + s[threadIdx.x] - v;  // exclusive
        dinv[i] = (v > 0) ? rsqrtf((float)v) : 0.0f;                // fused
    }
}

// ---------------- fill CSR: atomic-free scatter using precomputed ranks ----------------
// 4 edges/thread; 4 independent gather+store chains.

__global__ void fill_kernel(const int* __restrict__ src, const int* __restrict__ dst,
                            const int* __restrict__ rank, const int* __restrict__ row_start,
                            int* __restrict__ csr_src) {
    int e = (blockIdx.x * 256 + threadIdx.x) * 4;
    if (e >= N_EDGES) return;
    int4 s4 = *(const int4*)(src + e);
    int4 d4 = *(const int4*)(dst + e);
    int4 r4 = *(const int4*)(rank + e);
    csr_src[row_start[d4.x] + r4.x] = s4.x;
    csr_src[row_start[d4.y] + r4.y] = s4.y;
    csr_src[row_start[d4.z] + r4.z] = s4.z;
    csr_src[row_start[d4.w] + r4.w] = s4.w;
}

// ---------------- GEMM1: h1b = bf16( dinv[row] * (x @ W1) )  [50000x128] ----------------
// Column-split: grid.y in {0,1}, 64 cols/block -> 32 KB LDS.
// 64 rows x 64 cols per block; thread = 4 rows x 4 cols.

__global__ __launch_bounds__(256) void gemm1_kernel(const float* __restrict__ x,
                                                    const float* __restrict__ W,
                                                    const float* __restrict__ dinv,
                                                    unsigned short* __restrict__ h1b) {
    __shared__ float Wds[128 * 64];    // 32 KB
    int c0 = blockIdx.y * 64;          // column offset
    float4* Wds4 = (float4*)Wds;
    const float4* W4 = (const float4*)W;
    int cb4 = c0 >> 2;                 // 0 or 16
#pragma unroll
    for (int i = threadIdx.x; i < 128 * 16; i += 256) {
        int k = i >> 4, c4 = i & 15;
        Wds4[i] = W4[k * 32 + cb4 + c4];
    }
    __syncthreads();

    int tx = threadIdx.x & 15;        // col4 within the 64-col half
    int ty = threadIdx.x >> 4;        // 16 groups of 4 rows
    int row0 = blockIdx.x * 64 + ty * 4;

    const float4* xr[4];
    bool valid[4];
#pragma unroll
    for (int i = 0; i < 4; ++i) {
        int r = row0 + i;
        valid[i] = (r < N_NODES);
        xr[i] = (const float4*)(x + (size_t)(valid[i] ? r : 0) * 128);
    }

    float4 acc[4] = {};
#pragma unroll 2
    for (int k4 = 0; k4 < 32; ++k4) {
        float4 xv[4];
#pragma unroll
        for (int i = 0; i < 4; ++i) xv[i] = xr[i][k4];
#pragma unroll
        for (int kk = 0; kk < 4; ++kk) {
            float4 w = Wds4[(k4 * 4 + kk) * 16 + tx];
#pragma unroll
            for (int i = 0; i < 4; ++i) {
                float xs = ((const float*)&xv[i])[kk];
                acc[i].x += xs * w.x;
                acc[i].y += xs * w.y;
                acc[i].z += xs * w.z;
                acc[i].w += xs * w.w;
            }
        }
    }

#pragma unroll
    for (int i = 0; i < 4; ++i) {
        if (valid[i]) {
            int row = row0 + i;
            float dn = dinv[row];
            ushort4 o;
            o.x = f2bf(acc[i].x * dn);
            o.y = f2bf(acc[i].y * dn);
            o.z = f2bf(acc[i].z * dn);
            o.w = f2bf(acc[i].w * dn);
            *(ushort4*)(h1b + (size_t)row * 128 + c0 + tx * 4) = o;
        }
    }
}

// ---------------- agg1: a1[n] = relu(b1 + dinv[n] * sum h1b[src_e])  [128 ch bf16 rows] ----
// 1 wave/node; 4 groups of 16 lanes; lane loads one uint4 (8 bf16 ch); unroll 2
// -> 8 edges in flight per wave.

__global__ __launch_bounds__(256) void agg1_kernel(const int* __restrict__ csr_src,
                                                   const int* __restrict__ row_start,
                                                   const int* __restrict__ cnt,
                                                   const float* __restrict__ dinv,
                                                   const float* __restrict__ b1,
                                                   const unsigned short* __restrict__ h1b,
                                                   float* __restrict__ a1) {
    int node = blockIdx.x * 4 + (threadIdx.x >> 6);
    if (node >= N_NODES) return;
    int lane = threadIdx.x & 63;
    int grp = lane >> 4;         // 4 groups: edge j = grp + 4t
    int q   = lane & 15;         // uint4 slot (channels 8q..8q+7)
    int start = row_start[node];
    int m = cnt[node];

    float acc[8] = {};

    int j = grp;
    for (; j + 4 < m; j += 8) {
        int s0 = csr_src[start + j];
        int s1 = csr_src[start + j + 4];
        uint4 u0 = ((const uint4*)(h1b + (size_t)s0 * 128))[q];
        uint4 u1 = ((const uint4*)(h1b + (size_t)s1 * 128))[q];
        acc[0] += bflo(u0.x); acc[1] += bfhi(u0.x);
        acc[2] += bflo(u0.y); acc[3] += bfhi(u0.y);
        acc[4] += bflo(u0.z); acc[5] += bfhi(u0.z);
        acc[6] += bflo(u0.w); acc[7] += bfhi(u0.w);
        acc[0] += bflo(u1.x); acc[1] += bfhi(u1.x);
        acc[2] += bflo(u1.y); acc[3] += bfhi(u1.y);
        acc[4] += bflo(u1.z); acc[5] += bfhi(u1.z);
        acc[6] += bflo(u1.w); acc[7] += bfhi(u1.w);
    }
    if (j < m) {
        int s0 = csr_src[start + j];
        uint4 u0 = ((const uint4*)(h1b + (size_t)s0 * 128))[q];
        acc[0] += bflo(u0.x); acc[1] += bfhi(u0.x);
        acc[2] += bflo(u0.y); acc[3] += bfhi(u0.y);
        acc[4] += bflo(u0.z); acc[5] += bfhi(u0.z);
        acc[6] += bflo(u0.w); acc[7] += bfhi(u0.w);
    }

    // reduce across 4 groups (lane bits 4,5)
#pragma unroll
    for (int d = 16; d <= 32; d <<= 1) {
#pragma unroll
        for (int c = 0; c < 8; ++c) acc[c] += __shfl_xor(acc[c], d, 64);
    }

    if (lane < 16) {
        float dn = dinv[node];
        float4 bA = ((const float4*)b1)[2 * q];
        float4 bB = ((const float4*)b1)[2 * q + 1];
        float4 rA, rB;
        rA.x = fmaxf(acc[0] * dn + bA.x, 0.f);
        rA.y = fmaxf(acc[1] * dn + bA.y, 0.f);
        rA.z = fmaxf(acc[2] * dn + bA.z, 0.f);
        rA.w = fmaxf(acc[3] * dn + bA.w, 0.f);
        rB.x = fmaxf(acc[4] * dn + bB.x, 0.f);
        rB.y = fmaxf(acc[5] * dn + bB.y, 0.f);
        rB.z = fmaxf(acc[6] * dn + bB.z, 0.f);
        rB.w = fmaxf(acc[7] * dn + bB.w, 0.f);
        float4* o = (float4*)(a1 + (size_t)node * 128);
        o[2 * q] = rA;
        o[2 * q + 1] = rB;
    }
}

// ---------------- GEMM2: h2b = bf16( dinv[row] * (a1 @ W2) )  [50000x64] ----------------
// 64 rows x 64 cols per block; W2 fully in LDS (32 KB).

__global__ __launch_bounds__(256) void gemm2_kernel(const float* __restrict__ a1,
                                                    const float* __restrict__ W,
                                                    const float* __restrict__ dinv,
                                                    unsigned short* __restrict__ h2b) {
    __shared__ float Wds[128 * 64];    // 32 KB
    float4* Wds4 = (float4*)Wds;
    const float4* W4 = (const float4*)W;
#pragma unroll
    for (int i = threadIdx.x; i < 2048; i += 256) Wds4[i] = W4[i];
    __syncthreads();

    int tx = threadIdx.x & 15;        // col4 0..15
    int ty = threadIdx.x >> 4;        // 16 groups of 4 rows
    int row0 = blockIdx.x * 64 + ty * 4;

    const float4* xr[4];
    bool valid[4];
#pragma unroll
    for (int i = 0; i < 4; ++i) {
        int r = row0 + i;
        valid[i] = (r < N_NODES);
        xr[i] = (const float4*)(a1 + (size_t)(valid[i] ? r : 0) * 128);
    }

    float4 acc[4] = {};
#pragma unroll 2
    for (int k4 = 0; k4 < 32; ++k4) {
        float4 xv[4];
#pragma unroll
        for (int i = 0; i < 4; ++i) xv[i] = xr[i][k4];
#pragma unroll
        for (int kk = 0; kk < 4; ++kk) {
            float4 w = Wds4[(k4 * 4 + kk) * 16 + tx];
#pragma unroll
            for (int i = 0; i < 4; ++i) {
                float xs = ((const float*)&xv[i])[kk];
                acc[i].x += xs * w.x;
                acc[i].y += xs * w.y;
                acc[i].z += xs * w.z;
                acc[i].w += xs * w.w;
            }
        }
    }

#pragma unroll
    for (int i = 0; i < 4; ++i) {
        if (valid[i]) {
            int row = row0 + i;
            float dn = dinv[row];
            ushort4 o;
            o.x = f2bf(acc[i].x * dn);
            o.y = f2bf(acc[i].y * dn);
            o.z = f2bf(acc[i].z * dn);
            o.w = f2bf(acc[i].w * dn);
            *(ushort4*)(h2b + (size_t)row * 64 + tx * 4) = o;
        }
    }
}

// ---------------- agg2: out[n] = b2 + dinv[n] * sum h2b[src_e]  [64 ch bf16 rows] ----------
// 1 wave/node; 8 groups of 8 lanes; lane loads one uint4 (8 bf16 ch); unroll 2
// -> 16 edges in flight per wave.

__global__ __launch_bounds__(256) void agg2_kernel(const int* __restrict__ csr_src,
                                                   const int* __restrict__ row_start,
                                                   const int* __restrict__ cnt,
                                                   const float* __restrict__ dinv,
                                                   const float* __restrict__ b2,
                                                   const unsigned short* __restrict__ h2b,
                                                   float* __restrict__ out) {
    int node = blockIdx.x * 4 + (threadIdx.x >> 6);
    if (node >= N_NODES) return;
    int lane = threadIdx.x & 63;
    int grp = lane >> 3;         // 8 groups: edge j = grp + 8t
    int q   = lane & 7;          // uint4 slot (channels 8q..8q+7)
    int start = row_start[node];
    int m = cnt[node];

    float acc[8] = {};

    int j = grp;
    for (; j + 8 < m; j += 16) {
        int s0 = csr_src[start + j];
        int s1 = csr_src[start + j + 8];
        uint4 u0 = ((const uint4*)(h2b + (size_t)s0 * 64))[q];
        uint4 u1 = ((const uint4*)(h2b + (size_t)s1 * 64))[q];
        acc[0] += bflo(u0.x); acc[1] += bfhi(u0.x);
        acc[2] += bflo(u0.y); acc[3] += bfhi(u0.y);
        acc[4] += bflo(u0.z); acc[5] += bfhi(u0.z);
        acc[6] += bflo(u0.w); acc[7] += bfhi(u0.w);
        acc[0] += bflo(u1.x); acc[1] += bfhi(u1.x);
        acc[2] += bflo(u1.y); acc[3] += bfhi(u1.y);
        acc[4] += bflo(u1.z); acc[5] += bfhi(u1.z);
        acc[6] += bflo(u1.w); acc[7] += bfhi(u1.w);
    }
    if (j < m) {
        int s0 = csr_src[start + j];
        uint4 u0 = ((const uint4*)(h2b + (size_t)s0 * 64))[q];
        acc[0] += bflo(u0.x); acc[1] += bfhi(u0.x);
        acc[2] += bflo(u0.y); acc[3] += bfhi(u0.y);
        acc[4] += bflo(u0.z); acc[5] += bfhi(u0.z);
        acc[6] += bflo(u0.w); acc[7] += bfhi(u0.w);
    }

    // reduce across 8 groups (lane bits 3,4,5)
#pragma unroll
    for (int d = 8; d <= 32; d <<= 1) {
#pragma unroll
        for (int c = 0; c < 8; ++c) acc[c] += __shfl_xor(acc[c], d, 64);
    }

    if (lane < 8) {
        float dn = dinv[node];
        float4 bA = ((const float4*)b2)[2 * q];
        float4 bB = ((const float4*)b2)[2 * q + 1];
        float4 rA, rB;
        rA.x = acc[0] * dn + bA.x;
        rA.y = acc[1] * dn + bA.y;
        rA.z = acc[2] * dn + bA.z;
        rA.w = acc[3] * dn + bA.w;
        rB.x = acc[4] * dn + bB.x;
        rB.y = acc[5] * dn + bB.y;
        rB.z = acc[6] * dn + bB.z;
        rB.w = acc[7] * dn + bB.w;
        float4* o = (float4*)(out + (size_t)node * 64);
        o[2 * q] = rA;
        o[2 * q + 1] = rB;
    }
}

// ---------------- launch ----------------

extern "C" void kernel_launch(void* const* d_in, const int* in_sizes, int n_in,
                              void* d_out, int out_size, void* d_ws, size_t ws_size,
                              hipStream_t stream) {
    const float* x  = (const float*)d_in[0];
    const int*   ei = (const int*)d_in[1];       // [2, E]: src = ei[0..E), dst = ei[E..2E)
    const float* W1 = (const float*)d_in[2];
    const float* b1 = (const float*)d_in[3];
    const float* W2 = (const float*)d_in[4];
    const float* b2 = (const float*)d_in[5];
    float* out = (float*)d_out;

    const int* src = ei;
    const int* dst = ei + N_EDGES;

    // workspace layout (32-bit words)
    char* ws = (char*)d_ws;
    int*   cnt       = (int*)ws;                              // NPAD
    int*   row_start = cnt + NPAD;                            // NPAD
    int*   blockSums = row_start + NPAD;                      // 64
    float* dinv      = (float*)(blockSums + 64);              // NPAD
    int*   rank      = (int*)(dinv + NPAD);                   // N_EDGES
    int*   csr_src   = rank + N_EDGES;                        // N_EDGES
    unsigned short* h1b = (unsigned short*)(csr_src + N_EDGES); // 50000*128 bf16 (h2b aliases)
    float* a1        = (float*)(h1b + (size_t)N_NODES * HID_DIM); // 50000*128 fp32
    unsigned short* h2b = h1b;                                // reuse: h1b dead after agg1

    // 1. zero cnt; rank+histogram in one pass
    hipMemsetAsync(cnt, 0, NPAD * sizeof(int), stream);
    rank_hist_kernel<<<(N_EDGES / 4 + 255) / 256, 256, 0, stream>>>(dst, cnt, rank);

    // 2. exclusive scan cnt -> row_start (+ fused dinv)
    reduce_kernel<<<NB_SCAN, 1024, 0, stream>>>(cnt, blockSums);
    scan_sums_kernel<<<1, 64, 0, stream>>>(blockSums);
    scan_kernel<<<NB_SCAN, 1024, 0, stream>>>(cnt, blockSums, row_start, dinv);

    // 3. fill CSR (atomic-free)
    fill_kernel<<<(N_EDGES / 4 + 255) / 256, 256, 0, stream>>>(src, dst, rank, row_start, csr_src);

    // 4. h1b = bf16(dinv * (x @ W1))
    {
        dim3 g((N_NODES + 63) / 64, 2);
        gemm1_kernel<<<g, 256, 0, stream>>>(x, W1, dinv, h1b);
    }

    // 5. a1 = relu(b1 + dinv * gather-sum)
    agg1_kernel<<<(N_NODES + 3) / 4, 256, 0, stream>>>(csr_src, row_start, cnt, dinv, b1, h1b, a1);

    // 6. h2b = bf16(dinv * (a1 @ W2))
    gemm2_kernel<<<(N_NODES + 63) / 64, 256, 0, stream>>>(a1, W2, dinv, h2b);

    // 7. out = b2 + dinv * gather-sum
    agg2_kernel<<<(N_NODES + 3) / 4, 256, 0, stream>>>(csr_src, row_start, cnt, dinv, b2, h2b, out);
}

// Round 7
// 228.631 us; speedup vs baseline: 9.6607x; 1.0844x over previous
//
#include <hip/hip_runtime.h>

#define N_NODES 50000
#define N_EDGES 800000
#define IN_DIM  128
#define HID_DIM 128
#define OUT_DIM 64

#define NPAD 50176                          // N_NODES rounded up (alignment)
#define NB_SCAN ((N_NODES + 1023) / 1024)   // 49

typedef __attribute__((ext_vector_type(8))) short bf16x8;   // 8 bf16 in 4 VGPRs
typedef __attribute__((ext_vector_type(4))) float f32x4;

// float -> bf16 (round-to-nearest-even), as ushort
__device__ __forceinline__ unsigned short f2bf(float f) {
    unsigned u = __float_as_uint(f);
    u += 0x7fffu + ((u >> 16) & 1u);
    return (unsigned short)(u >> 16);
}
// bf16 pair unpack from a uint (little-endian: low ushort first)
__device__ __forceinline__ float bflo(unsigned u) { return __uint_as_float(u << 16); }
__device__ __forceinline__ float bfhi(unsigned u) { return __uint_as_float(u & 0xffff0000u); }

// ---------------- rank+histogram: rank[e] = old count of dst[e] ----------------

__global__ void rank_hist_kernel(const int* __restrict__ dst, int* __restrict__ cnt,
                                 int* __restrict__ rank) {
    int e = (blockIdx.x * 256 + threadIdx.x) * 4;
    if (e >= N_EDGES) return;                 // N_EDGES % 4 == 0 -> full int4 safe
    int4 d4 = *(const int4*)(dst + e);
    int r0 = atomicAdd(&cnt[d4.x], 1);
    int r1 = atomicAdd(&cnt[d4.y], 1);
    int r2 = atomicAdd(&cnt[d4.z], 1);
    int r3 = atomicAdd(&cnt[d4.w], 1);
    *(int4*)(rank + e) = make_int4(r0, r1, r2, r3);
}

// ---------------- exclusive scan of cnt -> row_start (+ fused dinv) ----------------

__global__ __launch_bounds__(1024) void reduce_kernel(const int* __restrict__ cnt,
                                                      int* __restrict__ blockSums) {
    __shared__ int s[1024];
    int i = blockIdx.x * 1024 + threadIdx.x;
    s[threadIdx.x] = (i < N_NODES) ? cnt[i] : 0;
    __syncthreads();
    for (int off = 512; off > 0; off >>= 1) {
        if (threadIdx.x < off) s[threadIdx.x] += s[threadIdx.x + off];
        __syncthreads();
    }
    if (threadIdx.x == 0) blockSums[blockIdx.x] = s[0];
}

// scan with inline prefix of blockSums (saves a dispatch)
__global__ __launch_bounds__(1024) void scan_kernel(const int* __restrict__ cnt,
                                                    const int* __restrict__ blockSums,
                                                    int* __restrict__ row_start,
                                                    float* __restrict__ dinv) {
    __shared__ int s[1024];
    __shared__ int sums[NB_SCAN];
    __shared__ int base_s;
    if (threadIdx.x < NB_SCAN) sums[threadIdx.x] = blockSums[threadIdx.x];
    int i = blockIdx.x * 1024 + threadIdx.x;
    int v = (i < N_NODES) ? cnt[i] : 0;
    s[threadIdx.x] = v;
    __syncthreads();
    if (threadIdx.x == 0) {
        int run = 0;
        for (int b = 0; b < (int)blockIdx.x; ++b) run += sums[b];
        base_s = run;
    }
    for (int off = 1; off < 1024; off <<= 1) {
        int t = (threadIdx.x >= off) ? s[threadIdx.x - off] : 0;
        __syncthreads();
        s[threadIdx.x] += t;
        __syncthreads();
    }
    if (i < N_NODES) {
        row_start[i] = base_s + s[threadIdx.x] - v;              // exclusive
        dinv[i] = (v > 0) ? rsqrtf((float)v) : 0.0f;             // fused
    }
}

// ---------------- fill CSR: atomic-free scatter using precomputed ranks ----------------

__global__ void fill_kernel(const int* __restrict__ src, const int* __restrict__ dst,
                            const int* __restrict__ rank, const int* __restrict__ row_start,
                            int* __restrict__ csr_src) {
    int e = (blockIdx.x * 256 + threadIdx.x) * 4;
    if (e >= N_EDGES) return;
    int4 s4 = *(const int4*)(src + e);
    int4 d4 = *(const int4*)(dst + e);
    int4 r4 = *(const int4*)(rank + e);
    csr_src[row_start[d4.x] + r4.x] = s4.x;
    csr_src[row_start[d4.y] + r4.y] = s4.y;
    csr_src[row_start[d4.z] + r4.z] = s4.z;
    csr_src[row_start[d4.w] + r4.w] = s4.w;
}

// ---------------- prep: x->bf16, W1->W1^T bf16, W2->W2^T bf16 ----------------
// blocks [0, 3125): x (8 floats/thread). block 3125..3140: W1T. 3141..3148: W2T.

#define XBLKS (N_NODES * IN_DIM / 8 / 256)   // 3125

__global__ void prep_kernel(const float* __restrict__ x, const float* __restrict__ W1,
                            const float* __restrict__ W2,
                            unsigned short* __restrict__ xb,
                            unsigned short* __restrict__ w1t,
                            unsigned short* __restrict__ w2t) {
    int bid = blockIdx.x;
    if (bid < XBLKS) {
        int i = (bid * 256 + threadIdx.x) * 8;
        float4 a = *(const float4*)(x + i);
        float4 b = *(const float4*)(x + i + 4);
        ushort4 o0, o1;
        o0.x = f2bf(a.x); o0.y = f2bf(a.y); o0.z = f2bf(a.z); o0.w = f2bf(a.w);
        o1.x = f2bf(b.x); o1.y = f2bf(b.y); o1.z = f2bf(b.z); o1.w = f2bf(b.w);
        *(ushort4*)(xb + i) = o0;
        *(ushort4*)(xb + i + 4) = o1;
    } else if (bid < XBLKS + 16) {
        // W1T[c][k] = bf16(W1[k][c]); 128x128. idx -> c = idx>>5, k4 = (idx&31)*4
        int idx = (bid - XBLKS) * 256 + threadIdx.x;     // 4096 threads
        int c = idx >> 5, k4 = (idx & 31) * 4;
        ushort4 o;
        o.x = f2bf(W1[(k4 + 0) * 128 + c]);
        o.y = f2bf(W1[(k4 + 1) * 128 + c]);
        o.z = f2bf(W1[(k4 + 2) * 128 + c]);
        o.w = f2bf(W1[(k4 + 3) * 128 + c]);
        *(ushort4*)(w1t + c * 128 + k4) = o;
    } else {
        // W2T[c][k] = bf16(W2[k][c]); 64x128. idx -> c = idx>>5, k4 = (idx&31)*4
        int idx = (bid - XBLKS - 16) * 256 + threadIdx.x; // 2048 threads
        if (idx >= 64 * 32) return;
        int c = idx >> 5, k4 = (idx & 31) * 4;
        ushort4 o;
        o.x = f2bf(W2[(k4 + 0) * 64 + c]);
        o.y = f2bf(W2[(k4 + 1) * 64 + c]);
        o.z = f2bf(W2[(k4 + 2) * 64 + c]);
        o.w = f2bf(W2[(k4 + 3) * 64 + c]);
        *(ushort4*)(w2t + c * 128 + k4) = o;
    }
}

// ---------------- GEMM1 (MFMA): h1b = bf16( dinv[row] * (xb @ W1) ) ----------------
// Wave = 16 rows x 128 cols (8 col-tiles). A[m=lane&15][k=quad*8+j];
// B from W1T (k-contiguous per col); C/D: col=lane&15, row=quad*4+reg.

__global__ __launch_bounds__(256) void gemm1_mfma(const unsigned short* __restrict__ xb,
                                                  const unsigned short* __restrict__ w1t,
                                                  const float* __restrict__ dinv,
                                                  unsigned short* __restrict__ h1b) {
    int wave = threadIdx.x >> 6;
    int lane = threadIdx.x & 63;
    int n = lane & 15, quad = lane >> 4;
    int row0 = blockIdx.x * 64 + wave * 16;

    int arow = row0 + n;
    if (arow >= N_NODES) arow = N_NODES - 1;             // clamp (stores guarded)
    const unsigned short* aptr = xb + (size_t)arow * 128 + quad * 8;
    const unsigned short* bbase = w1t + (size_t)n * 128 + quad * 8;

    f32x4 acc[8];
#pragma unroll
    for (int t = 0; t < 8; ++t) acc[t] = (f32x4){0.f, 0.f, 0.f, 0.f};

#pragma unroll
    for (int w4 = 0; w4 < 4; ++w4) {
        bf16x8 af = *(const bf16x8*)(aptr + w4 * 32);
#pragma unroll
        for (int t = 0; t < 8; ++t) {
            bf16x8 bf = *(const bf16x8*)(bbase + (size_t)t * 16 * 128 + w4 * 32);
            acc[t] = __builtin_amdgcn_mfma_f32_16x16x32_bf16(af, bf, acc[t], 0, 0, 0);
        }
    }

#pragma unroll
    for (int r = 0; r < 4; ++r) {
        int row = row0 + quad * 4 + r;
        if (row < N_NODES) {
            float dn = dinv[row];
            unsigned short* o = h1b + (size_t)row * 128 + n;
#pragma unroll
            for (int t = 0; t < 8; ++t) o[t * 16] = f2bf(acc[t][r] * dn);
        }
    }
}

// ---------------- GEMM2 (MFMA): h2b = bf16( dinv[row] * (a1b @ W2) ) ----------------
// Wave = 16 rows x 64 cols (4 col-tiles).

__global__ __launch_bounds__(256) void gemm2_mfma(const unsigned short* __restrict__ a1b,
                                                  const unsigned short* __restrict__ w2t,
                                                  const float* __restrict__ dinv,
                                                  unsigned short* __restrict__ h2b) {
    int wave = threadIdx.x >> 6;
    int lane = threadIdx.x & 63;
    int n = lane & 15, quad = lane >> 4;
    int row0 = blockIdx.x * 64 + wave * 16;

    int arow = row0 + n;
    if (arow >= N_NODES) arow = N_NODES - 1;
    const unsigned short* aptr = a1b + (size_t)arow * 128 + quad * 8;
    const unsigned short* bbase = w2t + (size_t)n * 128 + quad * 8;

    f32x4 acc[4];
#pragma unroll
    for (int t = 0; t < 4; ++t) acc[t] = (f32x4){0.f, 0.f, 0.f, 0.f};

#pragma unroll
    for (int w4 = 0; w4 < 4; ++w4) {
        bf16x8 af = *(const bf16x8*)(aptr + w4 * 32);
#pragma unroll
        for (int t = 0; t < 4; ++t) {
            bf16x8 bf = *(const bf16x8*)(bbase + (size_t)t * 16 * 128 + w4 * 32);
            acc[t] = __builtin_amdgcn_mfma_f32_16x16x32_bf16(af, bf, acc[t], 0, 0, 0);
        }
    }

#pragma unroll
    for (int r = 0; r < 4; ++r) {
        int row = row0 + quad * 4 + r;
        if (row < N_NODES) {
            float dn = dinv[row];
            unsigned short* o = h2b + (size_t)row * 64 + n;
#pragma unroll
            for (int t = 0; t < 4; ++t) o[t * 16] = f2bf(acc[t][r] * dn);
        }
    }
}

// ---------------- agg1: a1b = bf16(relu(b1 + dinv[n] * sum h1b[src_e]))  [128 ch] ----
// 1 wave/node; 4 groups of 16 lanes; lane loads one uint4 (8 bf16 ch); unroll 2.

__global__ __launch_bounds__(256) void agg1_kernel(const int* __restrict__ csr_src,
                                                   const int* __restrict__ row_start,
                                                   const int* __restrict__ cnt,
                                                   const float* __restrict__ dinv,
                                                   const float* __restrict__ b1,
                                                   const unsigned short* __restrict__ h1b,
                                                   unsigned short* __restrict__ a1b) {
    int node = blockIdx.x * 4 + (threadIdx.x >> 6);
    if (node >= N_NODES) return;
    int lane = threadIdx.x & 63;
    int grp = lane >> 4;         // 4 groups: edge j = grp + 4t
    int q   = lane & 15;         // uint4 slot (channels 8q..8q+7)
    int start = row_start[node];
    int m = cnt[node];

    float acc[8] = {};

    int j = grp;
    for (; j + 4 < m; j += 8) {
        int s0 = csr_src[start + j];
        int s1 = csr_src[start + j + 4];
        uint4 u0 = ((const uint4*)(h1b + (size_t)s0 * 128))[q];
        uint4 u1 = ((const uint4*)(h1b + (size_t)s1 * 128))[q];
        acc[0] += bflo(u0.x); acc[1] += bfhi(u0.x);
        acc[2] += bflo(u0.y); acc[3] += bfhi(u0.y);
        acc[4] += bflo(u0.z); acc[5] += bfhi(u0.z);
        acc[6] += bflo(u0.w); acc[7] += bfhi(u0.w);
        acc[0] += bflo(u1.x); acc[1] += bfhi(u1.x);
        acc[2] += bflo(u1.y); acc[3] += bfhi(u1.y);
        acc[4] += bflo(u1.z); acc[5] += bfhi(u1.z);
        acc[6] += bflo(u1.w); acc[7] += bfhi(u1.w);
    }
    if (j < m) {
        int s0 = csr_src[start + j];
        uint4 u0 = ((const uint4*)(h1b + (size_t)s0 * 128))[q];
        acc[0] += bflo(u0.x); acc[1] += bfhi(u0.x);
        acc[2] += bflo(u0.y); acc[3] += bfhi(u0.y);
        acc[4] += bflo(u0.z); acc[5] += bfhi(u0.z);
        acc[6] += bflo(u0.w); acc[7] += bfhi(u0.w);
    }

#pragma unroll
    for (int d = 16; d <= 32; d <<= 1) {
#pragma unroll
        for (int c = 0; c < 8; ++c) acc[c] += __shfl_xor(acc[c], d, 64);
    }

    if (lane < 16) {
        float dn = dinv[node];
        float4 bA = ((const float4*)b1)[2 * q];
        float4 bB = ((const float4*)b1)[2 * q + 1];
        ushort4 oA, oB;
        oA.x = f2bf(fmaxf(acc[0] * dn + bA.x, 0.f));
        oA.y = f2bf(fmaxf(acc[1] * dn + bA.y, 0.f));
        oA.z = f2bf(fmaxf(acc[2] * dn + bA.z, 0.f));
        oA.w = f2bf(fmaxf(acc[3] * dn + bA.w, 0.f));
        oB.x = f2bf(fmaxf(acc[4] * dn + bB.x, 0.f));
        oB.y = f2bf(fmaxf(acc[5] * dn + bB.y, 0.f));
        oB.z = f2bf(fmaxf(acc[6] * dn + bB.z, 0.f));
        oB.w = f2bf(fmaxf(acc[7] * dn + bB.w, 0.f));
        ushort4* o = (ushort4*)(a1b + (size_t)node * 128 + q * 8);
        o[0] = oA;
        o[1] = oB;
    }
}

// ---------------- agg2: out[n] = b2 + dinv[n] * sum h2b[src_e]  [64 ch] ----------

__global__ __launch_bounds__(256) void agg2_kernel(const int* __restrict__ csr_src,
                                                   const int* __restrict__ row_start,
                                                   const int* __restrict__ cnt,
                                                   const float* __restrict__ dinv,
                                                   const float* __restrict__ b2,
                                                   const unsigned short* __restrict__ h2b,
                                                   float* __restrict__ out) {
    int node = blockIdx.x * 4 + (threadIdx.x >> 6);
    if (node >= N_NODES) return;
    int lane = threadIdx.x & 63;
    int grp = lane >> 3;         // 8 groups: edge j = grp + 8t
    int q   = lane & 7;          // uint4 slot (channels 8q..8q+7)
    int start = row_start[node];
    int m = cnt[node];

    float acc[8] = {};

    int j = grp;
    for (; j + 8 < m; j += 16) {
        int s0 = csr_src[start + j];
        int s1 = csr_src[start + j + 8];
        uint4 u0 = ((const uint4*)(h2b + (size_t)s0 * 64))[q];
        uint4 u1 = ((const uint4*)(h2b + (size_t)s1 * 64))[q];
        acc[0] += bflo(u0.x); acc[1] += bfhi(u0.x);
        acc[2] += bflo(u0.y); acc[3] += bfhi(u0.y);
        acc[4] += bflo(u0.z); acc[5] += bfhi(u0.z);
        acc[6] += bflo(u0.w); acc[7] += bfhi(u0.w);
        acc[0] += bflo(u1.x); acc[1] += bfhi(u1.x);
        acc[2] += bflo(u1.y); acc[3] += bfhi(u1.y);
        acc[4] += bflo(u1.z); acc[5] += bfhi(u1.z);
        acc[6] += bflo(u1.w); acc[7] += bfhi(u1.w);
    }
    if (j < m) {
        int s0 = csr_src[start + j];
        uint4 u0 = ((const uint4*)(h2b + (size_t)s0 * 64))[q];
        acc[0] += bflo(u0.x); acc[1] += bfhi(u0.x);
        acc[2] += bflo(u0.y); acc[3] += bfhi(u0.y);
        acc[4] += bflo(u0.z); acc[5] += bfhi(u0.z);
        acc[6] += bflo(u0.w); acc[7] += bfhi(u0.w);
    }

#pragma unroll
    for (int d = 8; d <= 32; d <<= 1) {
#pragma unroll
        for (int c = 0; c < 8; ++c) acc[c] += __shfl_xor(acc[c], d, 64);
    }

    if (lane < 8) {
        float dn = dinv[node];
        float4 bA = ((const float4*)b2)[2 * q];
        float4 bB = ((const float4*)b2)[2 * q + 1];
        float4 rA, rB;
        rA.x = acc[0] * dn + bA.x;
        rA.y = acc[1] * dn + bA.y;
        rA.z = acc[2] * dn + bA.z;
        rA.w = acc[3] * dn + bA.w;
        rB.x = acc[4] * dn + bB.x;
        rB.y = acc[5] * dn + bB.y;
        rB.z = acc[6] * dn + bB.z;
        rB.w = acc[7] * dn + bB.w;
        float4* o = (float4*)(out + (size_t)node * 64);
        o[2 * q] = rA;
        o[2 * q + 1] = rB;
    }
}

// ---------------- launch ----------------

extern "C" void kernel_launch(void* const* d_in, const int* in_sizes, int n_in,
                              void* d_out, int out_size, void* d_ws, size_t ws_size,
                              hipStream_t stream) {
    const float* x  = (const float*)d_in[0];
    const int*   ei = (const int*)d_in[1];       // [2, E]: src = ei[0..E), dst = ei[E..2E)
    const float* W1 = (const float*)d_in[2];
    const float* b1 = (const float*)d_in[3];
    const float* W2 = (const float*)d_in[4];
    const float* b2 = (const float*)d_in[5];
    float* out = (float*)d_out;

    const int* src = ei;
    const int* dst = ei + N_EDGES;

    // workspace layout (32-bit words / ushort regions, all 16B-aligned)
    char* ws = (char*)d_ws;
    int*   cnt       = (int*)ws;                                 // NPAD
    int*   row_start = cnt + NPAD;                               // NPAD
    int*   blockSums = row_start + NPAD;                         // 64
    float* dinv      = (float*)(blockSums + 64);                 // NPAD
    int*   rank      = (int*)(dinv + NPAD);                      // N_EDGES
    int*   csr_src   = rank + N_EDGES;                           // N_EDGES
    unsigned short* h1b = (unsigned short*)(csr_src + N_EDGES);  // 50000*128 bf16
    unsigned short* a1b = h1b + (size_t)N_NODES * HID_DIM;       // 50000*128 bf16
    unsigned short* xb  = a1b + (size_t)N_NODES * HID_DIM;       // 50000*128 bf16
    unsigned short* w1t = xb + (size_t)N_NODES * IN_DIM;         // 128*128 bf16
    unsigned short* w2t = w1t + 128 * 128;                       // 64*128 bf16
    unsigned short* h2b = h1b;                                   // reuse: h1b dead after agg1

    // 1. zero cnt; rank+histogram in one pass
    hipMemsetAsync(cnt, 0, NPAD * sizeof(int), stream);
    rank_hist_kernel<<<(N_EDGES / 4 + 255) / 256, 256, 0, stream>>>(dst, cnt, rank);

    // 2. exclusive scan cnt -> row_start (+ fused dinv, inline block-sums prefix)
    reduce_kernel<<<NB_SCAN, 1024, 0, stream>>>(cnt, blockSums);
    scan_kernel<<<NB_SCAN, 1024, 0, stream>>>(cnt, blockSums, row_start, dinv);

    // 3. fill CSR (atomic-free)
    fill_kernel<<<(N_EDGES / 4 + 255) / 256, 256, 0, stream>>>(src, dst, rank, row_start, csr_src);

    // 4. prep: x->bf16, W1^T, W2^T
    prep_kernel<<<XBLKS + 24, 256, 0, stream>>>(x, W1, W2, xb, w1t, w2t);

    // 5. h1b = bf16(dinv * (xb @ W1))   [MFMA]
    gemm1_mfma<<<(N_NODES + 63) / 64, 256, 0, stream>>>(xb, w1t, dinv, h1b);

    // 6. a1b = bf16(relu(b1 + dinv * gather-sum))
    agg1_kernel<<<(N_NODES + 3) / 4, 256, 0, stream>>>(csr_src, row_start, cnt, dinv, b1, h1b, a1b);

    // 7. h2b = bf16(dinv * (a1b @ W2))  [MFMA]
    gemm2_mfma<<<(N_NODES + 63) / 64, 256, 0, stream>>>(a1b, w2t, dinv, h2b);

    // 8. out = b2 + dinv * gather-sum
    agg2_kernel<<<(N_NODES + 3) / 4, 256, 0, stream>>>(csr_src, row_start, cnt, dinv, b2, h2b, out);
}

// Round 8
// 213.445 us; speedup vs baseline: 10.3480x; 1.0711x over previous
//
#include <hip/hip_runtime.h>

#define N_NODES 50000
#define N_EDGES 800000
#define IN_DIM  128
#define HID_DIM 128
#define OUT_DIM 64

#define NPAD 50176                          // N_NODES rounded up (alignment)
#define NB_SCAN ((N_NODES + 1023) / 1024)   // 49
#define FILLB ((N_EDGES / 4 + 255) / 256)   // 782 fill blocks

typedef __attribute__((ext_vector_type(8))) short bf16x8;   // 8 bf16 in 4 VGPRs
typedef __attribute__((ext_vector_type(4))) float f32x4;

// float -> bf16 (round-to-nearest-even), as ushort
__device__ __forceinline__ unsigned short f2bf(float f) {
    unsigned u = __float_as_uint(f);
    u += 0x7fffu + ((u >> 16) & 1u);
    return (unsigned short)(u >> 16);
}
// bf16 pair unpack from a uint (little-endian: low ushort first)
__device__ __forceinline__ float bflo(unsigned u) { return __uint_as_float(u << 16); }
__device__ __forceinline__ float bfhi(unsigned u) { return __uint_as_float(u & 0xffff0000u); }

// ---------------- rank+histogram: rank[e] = old count of dst[e] ----------------

__global__ void rank_hist_kernel(const int* __restrict__ dst, int* __restrict__ cnt,
                                 int* __restrict__ rank) {
    int e = (blockIdx.x * 256 + threadIdx.x) * 4;
    if (e >= N_EDGES) return;                 // N_EDGES % 4 == 0 -> full int4 safe
    int4 d4 = *(const int4*)(dst + e);
    int r0 = atomicAdd(&cnt[d4.x], 1);
    int r1 = atomicAdd(&cnt[d4.y], 1);
    int r2 = atomicAdd(&cnt[d4.z], 1);
    int r3 = atomicAdd(&cnt[d4.w], 1);
    *(int4*)(rank + e) = make_int4(r0, r1, r2, r3);
}

// ---------------- exclusive scan of cnt -> row_start (+ fused dinv) ----------------

__global__ __launch_bounds__(1024) void reduce_kernel(const int* __restrict__ cnt,
                                                      int* __restrict__ blockSums) {
    __shared__ int s[1024];
    int i = blockIdx.x * 1024 + threadIdx.x;
    s[threadIdx.x] = (i < N_NODES) ? cnt[i] : 0;
    __syncthreads();
    for (int off = 512; off > 0; off >>= 1) {
        if (threadIdx.x < off) s[threadIdx.x] += s[threadIdx.x + off];
        __syncthreads();
    }
    if (threadIdx.x == 0) blockSums[blockIdx.x] = s[0];
}

__global__ __launch_bounds__(1024) void scan_kernel(const int* __restrict__ cnt,
                                                    const int* __restrict__ blockSums,
                                                    int* __restrict__ row_start,
                                                    float* __restrict__ dinv) {
    __shared__ int s[1024];
    __shared__ int sums[NB_SCAN];
    __shared__ int base_s;
    if (threadIdx.x < NB_SCAN) sums[threadIdx.x] = blockSums[threadIdx.x];
    int i = blockIdx.x * 1024 + threadIdx.x;
    int v = (i < N_NODES) ? cnt[i] : 0;
    s[threadIdx.x] = v;
    __syncthreads();
    if (threadIdx.x == 0) {
        int run = 0;
        for (int b = 0; b < (int)blockIdx.x; ++b) run += sums[b];
        base_s = run;
    }
    for (int off = 1; off < 1024; off <<= 1) {
        int t = (threadIdx.x >= off) ? s[threadIdx.x - off] : 0;
        __syncthreads();
        s[threadIdx.x] += t;
        __syncthreads();
    }
    if (i < N_NODES) {
        row_start[i] = base_s + s[threadIdx.x] - v;              // exclusive
        dinv[i] = (v > 0) ? rsqrtf((float)v) : 0.0f;             // fused
    }
}

// ---------------- fill CSR (atomic-free) + W1^T/W2^T bf16 prep (extra blocks) ------

__global__ void fill_kernel(const int* __restrict__ src, const int* __restrict__ dst,
                            const int* __restrict__ rank, const int* __restrict__ row_start,
                            int* __restrict__ csr_src,
                            const float* __restrict__ W1, const float* __restrict__ W2,
                            unsigned short* __restrict__ w1t, unsigned short* __restrict__ w2t) {
    int bid = blockIdx.x;
    if (bid < FILLB) {
        int e = (bid * 256 + threadIdx.x) * 4;
        if (e >= N_EDGES) return;
        int4 s4 = *(const int4*)(src + e);
        int4 d4 = *(const int4*)(dst + e);
        int4 r4 = *(const int4*)(rank + e);
        csr_src[row_start[d4.x] + r4.x] = s4.x;
        csr_src[row_start[d4.y] + r4.y] = s4.y;
        csr_src[row_start[d4.z] + r4.z] = s4.z;
        csr_src[row_start[d4.w] + r4.w] = s4.w;
    } else if (bid < FILLB + 16) {
        // W1T[c][k] = bf16(W1[k][c]); 128x128. idx -> c = idx>>5, k4 = (idx&31)*4
        int idx = (bid - FILLB) * 256 + threadIdx.x;     // 4096 threads
        int c = idx >> 5, k4 = (idx & 31) * 4;
        ushort4 o;
        o.x = f2bf(W1[(k4 + 0) * 128 + c]);
        o.y = f2bf(W1[(k4 + 1) * 128 + c]);
        o.z = f2bf(W1[(k4 + 2) * 128 + c]);
        o.w = f2bf(W1[(k4 + 3) * 128 + c]);
        *(ushort4*)(w1t + c * 128 + k4) = o;
    } else {
        // W2T[c][k] = bf16(W2[k][c]); 64x128. idx -> c = idx>>5, k4 = (idx&31)*4
        int idx = (bid - FILLB - 16) * 256 + threadIdx.x; // 2048 threads
        if (idx >= 64 * 32) return;
        int c = idx >> 5, k4 = (idx & 31) * 4;
        ushort4 o;
        o.x = f2bf(W2[(k4 + 0) * 64 + c]);
        o.y = f2bf(W2[(k4 + 1) * 64 + c]);
        o.z = f2bf(W2[(k4 + 2) * 64 + c]);
        o.w = f2bf(W2[(k4 + 3) * 64 + c]);
        *(ushort4*)(w2t + c * 128 + k4) = o;
    }
}

// ---------------- GEMM1 (MFMA, inline fp32->bf16 A-cast): h1b = bf16(dinv*(x @ W1)) ----
// Wave = 16 rows x 128 cols (8 col-tiles). A[m=lane&15][k=quad*8+j] cast from fp32 x;
// B from W1T (k-contiguous); C/D: col=lane&15, row=quad*4+reg.

__global__ __launch_bounds__(256) void gemm1_mfma(const float* __restrict__ x,
                                                  const unsigned short* __restrict__ w1t,
                                                  const float* __restrict__ dinv,
                                                  unsigned short* __restrict__ h1b) {
    int wave = threadIdx.x >> 6;
    int lane = threadIdx.x & 63;
    int n = lane & 15, quad = lane >> 4;
    int row0 = blockIdx.x * 64 + wave * 16;

    int arow = row0 + n;
    if (arow >= N_NODES) arow = N_NODES - 1;             // clamp (stores guarded)
    const float* aptr = x + (size_t)arow * 128 + quad * 8;
    const unsigned short* bbase = w1t + (size_t)n * 128 + quad * 8;

    f32x4 acc[8];
#pragma unroll
    for (int t = 0; t < 8; ++t) acc[t] = (f32x4){0.f, 0.f, 0.f, 0.f};

#pragma unroll
    for (int w4 = 0; w4 < 4; ++w4) {
        float4 f0 = *(const float4*)(aptr + w4 * 32);
        float4 f1 = *(const float4*)(aptr + w4 * 32 + 4);
        bf16x8 af;
        af[0] = (short)f2bf(f0.x); af[1] = (short)f2bf(f0.y);
        af[2] = (short)f2bf(f0.z); af[3] = (short)f2bf(f0.w);
        af[4] = (short)f2bf(f1.x); af[5] = (short)f2bf(f1.y);
        af[6] = (short)f2bf(f1.z); af[7] = (short)f2bf(f1.w);
#pragma unroll
        for (int t = 0; t < 8; ++t) {
            bf16x8 bf = *(const bf16x8*)(bbase + (size_t)t * 2048 + w4 * 32);
            acc[t] = __builtin_amdgcn_mfma_f32_16x16x32_bf16(af, bf, acc[t], 0, 0, 0);
        }
    }

#pragma unroll
    for (int r = 0; r < 4; ++r) {
        int row = row0 + quad * 4 + r;
        if (row < N_NODES) {
            float dn = dinv[row];
            unsigned short* o = h1b + (size_t)row * 128 + n;
#pragma unroll
            for (int t = 0; t < 8; ++t) o[t * 16] = f2bf(acc[t][r] * dn);
        }
    }
}

// ---------------- fused agg1 + GEMM2 ----------------
// Block = 16 consecutive nodes (grid 3125, exact).
// Phase 1: 16 lane-groups of 16; group g aggregates node0+g's h1b rows (4 gathers in
//   flight), applies dinv+bias+relu, writes bf16 into LDS tile a1t[16][136] (pad=8).
// Phase 2: wave w computes h2b cols [16w,16w+16) for the 16 rows via 4 MFMA from LDS.

#define A1T_STRIDE 136

__global__ __launch_bounds__(256) void agg1_gemm2_fused(const int* __restrict__ csr_src,
                                                        const int* __restrict__ row_start,
                                                        const int* __restrict__ cnt,
                                                        const float* __restrict__ dinv,
                                                        const float* __restrict__ b1,
                                                        const unsigned short* __restrict__ h1b,
                                                        const unsigned short* __restrict__ w2t,
                                                        unsigned short* __restrict__ h2b) {
    __shared__ unsigned short a1t[16 * A1T_STRIDE];      // 16 x 128 bf16, padded

    int node0 = blockIdx.x * 16;
    int g = threadIdx.x >> 4;        // node within block
    int q = threadIdx.x & 15;        // uint4 slot (channels 8q..8q+7)
    int node = node0 + g;            // always < N_NODES (50000 = 3125*16)
    int start = row_start[node];
    int m = cnt[node];

    float acc[8] = {};
    int j = 0;
    for (; j + 3 < m; j += 4) {
        int s0 = csr_src[start + j];
        int s1 = csr_src[start + j + 1];
        int s2 = csr_src[start + j + 2];
        int s3 = csr_src[start + j + 3];
        uint4 u0 = ((const uint4*)(h1b + (size_t)s0 * 128))[q];
        uint4 u1 = ((const uint4*)(h1b + (size_t)s1 * 128))[q];
        uint4 u2 = ((const uint4*)(h1b + (size_t)s2 * 128))[q];
        uint4 u3 = ((const uint4*)(h1b + (size_t)s3 * 128))[q];
        acc[0] += bflo(u0.x); acc[1] += bfhi(u0.x);
        acc[2] += bflo(u0.y); acc[3] += bfhi(u0.y);
        acc[4] += bflo(u0.z); acc[5] += bfhi(u0.z);
        acc[6] += bflo(u0.w); acc[7] += bfhi(u0.w);
        acc[0] += bflo(u1.x); acc[1] += bfhi(u1.x);
        acc[2] += bflo(u1.y); acc[3] += bfhi(u1.y);
        acc[4] += bflo(u1.z); acc[5] += bfhi(u1.z);
        acc[6] += bflo(u1.w); acc[7] += bfhi(u1.w);
        acc[0] += bflo(u2.x); acc[1] += bfhi(u2.x);
        acc[2] += bflo(u2.y); acc[3] += bfhi(u2.y);
        acc[4] += bflo(u2.z); acc[5] += bfhi(u2.z);
        acc[6] += bflo(u2.w); acc[7] += bfhi(u2.w);
        acc[0] += bflo(u3.x); acc[1] += bfhi(u3.x);
        acc[2] += bflo(u3.y); acc[3] += bfhi(u3.y);
        acc[4] += bflo(u3.z); acc[5] += bfhi(u3.z);
        acc[6] += bflo(u3.w); acc[7] += bfhi(u3.w);
    }
    for (; j < m; ++j) {
        int s0 = csr_src[start + j];
        uint4 u0 = ((const uint4*)(h1b + (size_t)s0 * 128))[q];
        acc[0] += bflo(u0.x); acc[1] += bfhi(u0.x);
        acc[2] += bflo(u0.y); acc[3] += bfhi(u0.y);
        acc[4] += bflo(u0.z); acc[5] += bfhi(u0.z);
        acc[6] += bflo(u0.w); acc[7] += bfhi(u0.w);
    }

    {
        float dn = dinv[node];
        float4 bA = ((const float4*)b1)[2 * q];
        float4 bB = ((const float4*)b1)[2 * q + 1];
        ushort4 oA, oB;
        oA.x = f2bf(fmaxf(acc[0] * dn + bA.x, 0.f));
        oA.y = f2bf(fmaxf(acc[1] * dn + bA.y, 0.f));
        oA.z = f2bf(fmaxf(acc[2] * dn + bA.z, 0.f));
        oA.w = f2bf(fmaxf(acc[3] * dn + bA.w, 0.f));
        oB.x = f2bf(fmaxf(acc[4] * dn + bB.x, 0.f));
        oB.y = f2bf(fmaxf(acc[5] * dn + bB.y, 0.f));
        oB.z = f2bf(fmaxf(acc[6] * dn + bB.z, 0.f));
        oB.w = f2bf(fmaxf(acc[7] * dn + bB.w, 0.f));
        ushort4* o = (ushort4*)(a1t + g * A1T_STRIDE + q * 8);
        o[0] = oA;
        o[1] = oB;
    }
    __syncthreads();

    // Phase 2: MFMA 16 rows x 16 cols per wave
    int wave = threadIdx.x >> 6;
    int lane = threadIdx.x & 63;
    int n = lane & 15, quad = lane >> 4;
    const unsigned short* bbase = w2t + (size_t)(wave * 16 + n) * 128 + quad * 8;
    const unsigned short* abase = a1t + (size_t)n * A1T_STRIDE + quad * 8;

    f32x4 c2 = (f32x4){0.f, 0.f, 0.f, 0.f};
#pragma unroll
    for (int w4 = 0; w4 < 4; ++w4) {
        bf16x8 af = *(const bf16x8*)(abase + w4 * 32);
        bf16x8 bf = *(const bf16x8*)(bbase + w4 * 32);
        c2 = __builtin_amdgcn_mfma_f32_16x16x32_bf16(af, bf, c2, 0, 0, 0);
    }

#pragma unroll
    for (int r = 0; r < 4; ++r) {
        int row = node0 + quad * 4 + r;
        float dn = dinv[row];
        h2b[(size_t)row * 64 + wave * 16 + n] = f2bf(c2[r] * dn);
    }
}

// ---------------- agg2: out[n] = b2 + dinv[n] * sum h2b[src_e]  [64 ch] ----------

__global__ __launch_bounds__(256) void agg2_kernel(const int* __restrict__ csr_src,
                                                   const int* __restrict__ row_start,
                                                   const int* __restrict__ cnt,
                                                   const float* __restrict__ dinv,
                                                   const float* __restrict__ b2,
                                                   const unsigned short* __restrict__ h2b,
                                                   float* __restrict__ out) {
    int node = blockIdx.x * 4 + (threadIdx.x >> 6);
    if (node >= N_NODES) return;
    int lane = threadIdx.x & 63;
    int grp = lane >> 3;         // 8 groups: edge j = grp + 8t
    int q   = lane & 7;          // uint4 slot (channels 8q..8q+7)
    int start = row_start[node];
    int m = cnt[node];

    float acc[8] = {};

    int j = grp;
    for (; j + 8 < m; j += 16) {
        int s0 = csr_src[start + j];
        int s1 = csr_src[start + j + 8];
        uint4 u0 = ((const uint4*)(h2b + (size_t)s0 * 64))[q];
        uint4 u1 = ((const uint4*)(h2b + (size_t)s1 * 64))[q];
        acc[0] += bflo(u0.x); acc[1] += bfhi(u0.x);
        acc[2] += bflo(u0.y); acc[3] += bfhi(u0.y);
        acc[4] += bflo(u0.z); acc[5] += bfhi(u0.z);
        acc[6] += bflo(u0.w); acc[7] += bfhi(u0.w);
        acc[0] += bflo(u1.x); acc[1] += bfhi(u1.x);
        acc[2] += bflo(u1.y); acc[3] += bfhi(u1.y);
        acc[4] += bflo(u1.z); acc[5] += bfhi(u1.z);
        acc[6] += bflo(u1.w); acc[7] += bfhi(u1.w);
    }
    if (j < m) {
        int s0 = csr_src[start + j];
        uint4 u0 = ((const uint4*)(h2b + (size_t)s0 * 64))[q];
        acc[0] += bflo(u0.x); acc[1] += bfhi(u0.x);
        acc[2] += bflo(u0.y); acc[3] += bfhi(u0.y);
        acc[4] += bflo(u0.z); acc[5] += bfhi(u0.z);
        acc[6] += bflo(u0.w); acc[7] += bfhi(u0.w);
    }

#pragma unroll
    for (int d = 8; d <= 32; d <<= 1) {
#pragma unroll
        for (int c = 0; c < 8; ++c) acc[c] += __shfl_xor(acc[c], d, 64);
    }

    if (lane < 8) {
        float dn = dinv[node];
        float4 bA = ((const float4*)b2)[2 * q];
        float4 bB = ((const float4*)b2)[2 * q + 1];
        float4 rA, rB;
        rA.x = acc[0] * dn + bA.x;
        rA.y = acc[1] * dn + bA.y;
        rA.z = acc[2] * dn + bA.z;
        rA.w = acc[3] * dn + bA.w;
        rB.x = acc[4] * dn + bB.x;
        rB.y = acc[5] * dn + bB.y;
        rB.z = acc[6] * dn + bB.z;
        rB.w = acc[7] * dn + bB.w;
        float4* o = (float4*)(out + (size_t)node * 64);
        o[2 * q] = rA;
        o[2 * q + 1] = rB;
    }
}

// ---------------- launch ----------------

extern "C" void kernel_launch(void* const* d_in, const int* in_sizes, int n_in,
                              void* d_out, int out_size, void* d_ws, size_t ws_size,
                              hipStream_t stream) {
    const float* x  = (const float*)d_in[0];
    const int*   ei = (const int*)d_in[1];       // [2, E]: src = ei[0..E), dst = ei[E..2E)
    const float* W1 = (const float*)d_in[2];
    const float* b1 = (const float*)d_in[3];
    const float* W2 = (const float*)d_in[4];
    const float* b2 = (const float*)d_in[5];
    float* out = (float*)d_out;

    const int* src = ei;
    const int* dst = ei + N_EDGES;

    // workspace layout (32-bit words / ushort regions, all 16B-aligned)
    char* ws = (char*)d_ws;
    int*   cnt       = (int*)ws;                                 // NPAD
    int*   row_start = cnt + NPAD;                               // NPAD
    int*   blockSums = row_start + NPAD;                         // 64
    float* dinv      = (float*)(blockSums + 64);                 // NPAD
    int*   rank      = (int*)(dinv + NPAD);                      // N_EDGES
    int*   csr_src   = rank + N_EDGES;                           // N_EDGES
    unsigned short* h1b = (unsigned short*)(csr_src + N_EDGES);  // 50000*128 bf16
    unsigned short* h2b = h1b + (size_t)N_NODES * HID_DIM;       // 50000*64 bf16 (NOT aliased:
                                                                 // fused kernel reads h1b while writing h2b)
    unsigned short* w1t = h2b + (size_t)N_NODES * OUT_DIM;       // 128*128 bf16
    unsigned short* w2t = w1t + 128 * 128;                       // 64*128 bf16

    // 1. zero cnt; rank+histogram in one pass
    hipMemsetAsync(cnt, 0, NPAD * sizeof(int), stream);
    rank_hist_kernel<<<(N_EDGES / 4 + 255) / 256, 256, 0, stream>>>(dst, cnt, rank);

    // 2. exclusive scan cnt -> row_start (+ fused dinv, inline block-sums prefix)
    reduce_kernel<<<NB_SCAN, 1024, 0, stream>>>(cnt, blockSums);
    scan_kernel<<<NB_SCAN, 1024, 0, stream>>>(cnt, blockSums, row_start, dinv);

    // 3. fill CSR (atomic-free) + W1^T/W2^T bf16 prep
    fill_kernel<<<FILLB + 24, 256, 0, stream>>>(src, dst, rank, row_start, csr_src,
                                                W1, W2, w1t, w2t);

    // 4. h1b = bf16(dinv * (x @ W1))   [MFMA, inline A-cast]
    gemm1_mfma<<<(N_NODES + 63) / 64, 256, 0, stream>>>(x, w1t, dinv, h1b);

    // 5+6. fused: a1 = relu(b1 + dinv*gather(h1b));  h2b = bf16(dinv * (a1 @ W2))
    agg1_gemm2_fused<<<N_NODES / 16, 256, 0, stream>>>(csr_src, row_start, cnt, dinv,
                                                       b1, h1b, w2t, h2b);

    // 7. out = b2 + dinv * gather-sum
    agg2_kernel<<<(N_NODES + 3) / 4, 256, 0, stream>>>(csr_src, row_start, cnt, dinv, b2, h2b, out);
}